// Round 8
// baseline (563.365 us; speedup 1.0000x reference)
//
#include <hip/hip_runtime.h>

#define B_ 4
#define S_ 2048
#define C_ 512
#define H_ 8
#define D_ 64
#define M_ 8192   // B_*S_

typedef short s8v __attribute__((ext_vector_type(8)));   // 8 bf16 (4 VGPRs)
typedef short s4v __attribute__((ext_vector_type(4)));   // 4 bf16 (2 VGPRs)
typedef float f4v __attribute__((ext_vector_type(4)));   // MFMA C/D
typedef unsigned short u16;
typedef unsigned int u32;

__device__ __forceinline__ u16 f2b(float f) {
    u32 u = __builtin_bit_cast(u32, f);
    u = u + 0x7fffu + ((u >> 16) & 1u);
    return (u16)(u >> 16);
}

// async 16B global->LDS; lds dest is wave-uniform base, lane i lands at +16*i
__device__ __forceinline__ void gl2lds16(const void* g, void* l) {
    __builtin_amdgcn_global_load_lds(
        (const __attribute__((address_space(1))) void*)g,
        (__attribute__((address_space(3))) void*)l, 16, 0, 0);
}

// ---------------------------------------------------------------------------
__global__ __launch_bounds__(256) void conv_k(const float* __restrict__ s,
                                              u16* __restrict__ d) {
    const int i = (blockIdx.x * 256 + threadIdx.x) * 4;
    const float4 v = *(const float4*)&s[i];
    ushort4 o;
    o.x = f2b(v.x); o.y = f2b(v.y); o.z = f2b(v.z); o.w = f2b(v.w);
    *(ushort4*)&d[i] = o;
}

// ---------------------------------------------------------------------------
// All six weight transposes in ONE launch: blockIdx.z selects the matrix.
// ---------------------------------------------------------------------------
__global__ __launch_bounds__(256) void trconv6_k(const float* __restrict__ s0,
                                                 const float* __restrict__ s1,
                                                 const float* __restrict__ s2,
                                                 const float* __restrict__ s3,
                                                 const float* __restrict__ s4,
                                                 const float* __restrict__ s5,
                                                 u16* __restrict__ d0,
                                                 u16* __restrict__ d1,
                                                 u16* __restrict__ d2,
                                                 u16* __restrict__ d3,
                                                 u16* __restrict__ d4,
                                                 u16* __restrict__ d5)
{
    const float* W; u16* Wt;
    switch (blockIdx.z) {
        case 0: W = s0; Wt = d0; break;
        case 1: W = s1; Wt = d1; break;
        case 2: W = s2; Wt = d2; break;
        case 3: W = s3; Wt = d3; break;
        case 4: W = s4; Wt = d4; break;
        default: W = s5; Wt = d5; break;
    }
    __shared__ float t[32][33];
    const int tx = threadIdx.x & 31, ty = threadIdx.x >> 5;
    const int n0 = blockIdx.x * 32, k0 = blockIdx.y * 32;
    #pragma unroll
    for (int i = 0; i < 4; ++i)
        t[ty + i * 8][tx] = W[(size_t)(k0 + ty + i * 8) * C_ + n0 + tx];
    __syncthreads();
    #pragma unroll
    for (int i = 0; i < 4; ++i)
        Wt[(size_t)(n0 + ty + i * 8) * C_ + k0 + tx] = f2b(t[tx][ty + i * 8]);
}

// ---------------------------------------------------------------------------
// Fused QKV projection (128x128 tiles, grid (12,64)). V output is written
// TRANSPOSED (plain, no swizzle) into Vt[b,h,d,s].
// ---------------------------------------------------------------------------
__global__ __launch_bounds__(256) void qkv_k(const u16* __restrict__ A,
                                             const u16* __restrict__ Wq,
                                             const u16* __restrict__ Wk,
                                             const u16* __restrict__ Wv,
                                             u16* __restrict__ oq,
                                             u16* __restrict__ ok,
                                             u16* __restrict__ ovt)
{
    __shared__ u16 As[2][8][16][32];
    __shared__ u16 Bs[2][8][16][32];
    const int tid = threadIdx.x;
    const int lane = tid & 63, w = tid >> 6;
    const int q4 = lane >> 4, l16 = lane & 15;
    const int wr = w >> 1, wc = w & 1;
    const int nt = blockIdx.x, which = nt >> 2;
    const u16* Bt = which == 0 ? Wq : (which == 1 ? Wk : Wv);
    const int bm = blockIdx.y * 128, bn = (nt & 3) * 128;
    const int lr = lane >> 2, lc = (lane & 3) * 8;

    f4v acc[4][4];
    #pragma unroll
    for (int i = 0; i < 4; ++i)
        #pragma unroll
        for (int j = 0; j < 4; ++j) acc[i][j] = (f4v){0.f, 0.f, 0.f, 0.f};

    #pragma unroll
    for (int r = 0; r < 2; ++r) {
        const int seg = r * 4 + w;
        const int row = seg * 16 + lr;
        gl2lds16(A  + (size_t)(bm + row) * C_ + lc, (char*)As + seg * 1024);
        gl2lds16(Bt + (size_t)(bn + row) * C_ + lc, (char*)Bs + seg * 1024);
    }
    for (int kt = 0; kt < 16; ++kt) {
        __syncthreads();
        const int buf = kt & 1;
        if (kt < 15) {
            const int nb = buf ^ 1, k0 = (kt + 1) * 32;
            #pragma unroll
            for (int r = 0; r < 2; ++r) {
                const int seg = r * 4 + w;
                const int row = seg * 16 + lr;
                gl2lds16(A  + (size_t)(bm + row) * C_ + k0 + lc, (char*)As + nb * 8192 + seg * 1024);
                gl2lds16(Bt + (size_t)(bn + row) * C_ + k0 + lc, (char*)Bs + nb * 8192 + seg * 1024);
            }
        }
        s8v a[4], bf[4];
        #pragma unroll
        for (int i = 0; i < 4; ++i) {
            const int row = wr * 64 + i * 16 + l16;
            a[i] = *(const s8v*)&As[buf][row >> 4][row & 15][q4 * 8];
        }
        #pragma unroll
        for (int j = 0; j < 4; ++j) {
            const int row = wc * 64 + j * 16 + l16;
            bf[j] = *(const s8v*)&Bs[buf][row >> 4][row & 15][q4 * 8];
        }
        #pragma unroll
        for (int i = 0; i < 4; ++i)
            #pragma unroll
            for (int j = 0; j < 4; ++j)
                acc[i][j] = __builtin_amdgcn_mfma_f32_16x16x32_bf16(a[i], bf[j], acc[i][j], 0, 0, 0);
    }

    if (which != 2) {
        u16* outp = which == 0 ? oq : ok;
        #pragma unroll
        for (int j = 0; j < 4; ++j) {
            const int n = bn + wc * 64 + j * 16 + l16;
            #pragma unroll
            for (int i = 0; i < 4; ++i) {
                const int m = bm + wr * 64 + i * 16 + q4 * 4;
                #pragma unroll
                for (int reg = 0; reg < 4; ++reg)
                    outp[(size_t)(m + reg) * C_ + n] = f2b(acc[i][j][reg]);
            }
        }
    } else {
        // V: plain transposed write. m -> s, n -> (h,d).
        const int bglob = bm >> 11;
        const int sbase = bm & (S_ - 1);
        #pragma unroll
        for (int j = 0; j < 4; ++j) {
            const int n = bn + wc * 64 + j * 16 + l16;
            const int h = n >> 6, d = n & 63;
            u16* vrow = ovt + ((size_t)(bglob * H_ + h) * D_ + d) * S_;
            #pragma unroll
            for (int i = 0; i < 4; ++i) {
                const int s = sbase + wr * 64 + i * 16 + q4 * 4;
                s4v pv;
                #pragma unroll
                for (int reg = 0; reg < 4; ++reg) pv[reg] = (short)f2b(acc[i][j][reg]);
                *(s4v*)&vrow[s] = pv;
            }
        }
    }
}

// ---------------------------------------------------------------------------
// BARRIER-FREE fused GEMM (32m x 512n row-complete) + LayerNorm epilogue.
// 512 threads = 8 waves; wave w owns n-cols [w*64, w*64+64). A and B frags
// load DIRECTLY global->VGPR with a 3-stage rotating register pipeline
// (prefetch kt+2); no LDS in the k-loop, no barriers until the LN epilogue.
// h = A@Bt (+bias) (+res);  y = LN(h)*wA+bA.
// TWO_LN: out1 = y (fp32), out2 = bf16(LN(y)*wB+bB).
// else:   y -> out1 (fp32) if !OB else out2 (bf16).
// ---------------------------------------------------------------------------
template <bool HAS_BIAS, bool HAS_RES, bool TWO_LN, bool OB>
__global__ __launch_bounds__(512) void fgemm_k(const u16* __restrict__ A,
                                               const u16* __restrict__ Bt,
                                               const float* __restrict__ bias,
                                               const float* __restrict__ res,
                                               const float* __restrict__ wA,
                                               const float* __restrict__ bA,
                                               const float* __restrict__ wB,
                                               const float* __restrict__ bB,
                                               float* __restrict__ out1,
                                               u16* __restrict__ out2)
{
    __shared__ float2 red[8][32];
    const int tid = threadIdx.x;
    const int lane = tid & 63, w = tid >> 6;
    const int q4 = lane >> 4, l16 = lane & 15;
    const int bm = blockIdx.x * 32;

    f4v acc[2][4];
    #pragma unroll
    for (int i = 0; i < 2; ++i)
        #pragma unroll
        for (int j = 0; j < 4; ++j) acc[i][j] = (f4v){0.f, 0.f, 0.f, 0.f};

    s8v af[3][2], bf[3][4];

#define LDAB(SLOT, KT) do {                                                     \
    _Pragma("unroll")                                                           \
    for (int i = 0; i < 2; ++i)                                                 \
        af[SLOT][i] = *(const s8v*)&A[(size_t)(bm + i * 16 + l16) * C_          \
                                      + (KT) * 32 + q4 * 8];                    \
    _Pragma("unroll")                                                           \
    for (int j = 0; j < 4; ++j)                                                 \
        bf[SLOT][j] = *(const s8v*)&Bt[(size_t)(w * 64 + j * 16 + l16) * C_     \
                                       + (KT) * 32 + q4 * 8];                   \
} while (0)

    LDAB(0, 0);
    LDAB(1, 1);
    #pragma unroll
    for (int kt = 0; kt < 16; ++kt) {
        const int cur = kt % 3;
        if (kt < 14) { LDAB((kt + 2) % 3, kt + 2); }
        #pragma unroll
        for (int i = 0; i < 2; ++i)
            #pragma unroll
            for (int j = 0; j < 4; ++j)
                acc[i][j] = __builtin_amdgcn_mfma_f32_16x16x32_bf16(af[cur][i], bf[cur][j], acc[i][j], 0, 0, 0);
    }
#undef LDAB

    // ------ epilogue: bias + residual, LN over the full 512-row ------
    if constexpr (HAS_BIAS) {
        #pragma unroll
        for (int j = 0; j < 4; ++j) {
            const float bj = bias[w * 64 + j * 16 + l16];
            #pragma unroll
            for (int i = 0; i < 2; ++i)
                #pragma unroll
                for (int reg = 0; reg < 4; ++reg) acc[i][j][reg] += bj;
        }
    }
    if constexpr (HAS_RES) {
        #pragma unroll
        for (int i = 0; i < 2; ++i)
            #pragma unroll
            for (int reg = 0; reg < 4; ++reg) {
                const float* rp = res + (size_t)(bm + i * 16 + q4 * 4 + reg) * C_;
                #pragma unroll
                for (int j = 0; j < 4; ++j)
                    acc[i][j][reg] += rp[w * 64 + j * 16 + l16];
            }
    }

    // stats pass 1
    float mean1[2][4], rstd1[2][4];
    #pragma unroll
    for (int i = 0; i < 2; ++i)
        #pragma unroll
        for (int reg = 0; reg < 4; ++reg) {
            float s = 0.f, ss = 0.f;
            #pragma unroll
            for (int j = 0; j < 4; ++j) {
                const float v = acc[i][j][reg];
                s += v; ss += v * v;
            }
            #pragma unroll
            for (int off = 1; off <= 8; off <<= 1) {
                s  += __shfl_xor(s, off);
                ss += __shfl_xor(ss, off);
            }
            if (l16 == 0) red[w][i * 16 + q4 * 4 + reg] = make_float2(s, ss);
        }
    __syncthreads();
    #pragma unroll
    for (int i = 0; i < 2; ++i)
        #pragma unroll
        for (int reg = 0; reg < 4; ++reg) {
            const int r = i * 16 + q4 * 4 + reg;
            float S = 0.f, SS = 0.f;
            #pragma unroll
            for (int ww = 0; ww < 8; ++ww) {
                const float2 f2 = red[ww][r];
                S += f2.x; SS += f2.y;
            }
            const float mn = S * (1.0f / C_);
            mean1[i][reg] = mn;
            rstd1[i][reg] = rsqrtf(SS * (1.0f / C_) - mn * mn + 1e-5f);
        }

    // y = (h - mean)*rstd*wA + bA  (in place)
    #pragma unroll
    for (int j = 0; j < 4; ++j) {
        const int n = w * 64 + j * 16 + l16;
        const float wj = wA[n], bj = bA[n];
        #pragma unroll
        for (int i = 0; i < 2; ++i)
            #pragma unroll
            for (int reg = 0; reg < 4; ++reg)
                acc[i][j][reg] = (acc[i][j][reg] - mean1[i][reg]) * rstd1[i][reg] * wj + bj;
    }

    if constexpr (TWO_LN) {
        #pragma unroll
        for (int i = 0; i < 2; ++i)
            #pragma unroll
            for (int reg = 0; reg < 4; ++reg) {
                float* op = out1 + (size_t)(bm + i * 16 + q4 * 4 + reg) * C_;
                #pragma unroll
                for (int j = 0; j < 4; ++j)
                    op[w * 64 + j * 16 + l16] = acc[i][j][reg];
            }
        float mean2[2][4], rstd2[2][4];
        __syncthreads();
        #pragma unroll
        for (int i = 0; i < 2; ++i)
            #pragma unroll
            for (int reg = 0; reg < 4; ++reg) {
                float s = 0.f, ss = 0.f;
                #pragma unroll
                for (int j = 0; j < 4; ++j) {
                    const float v = acc[i][j][reg];
                    s += v; ss += v * v;
                }
                #pragma unroll
                for (int off = 1; off <= 8; off <<= 1) {
                    s  += __shfl_xor(s, off);
                    ss += __shfl_xor(ss, off);
                }
                if (l16 == 0) red[w][i * 16 + q4 * 4 + reg] = make_float2(s, ss);
            }
        __syncthreads();
        #pragma unroll
        for (int i = 0; i < 2; ++i)
            #pragma unroll
            for (int reg = 0; reg < 4; ++reg) {
                const int r = i * 16 + q4 * 4 + reg;
                float S = 0.f, SS = 0.f;
                #pragma unroll
                for (int ww = 0; ww < 8; ++ww) {
                    const float2 f2 = red[ww][r];
                    S += f2.x; SS += f2.y;
                }
                const float mn = S * (1.0f / C_);
                mean2[i][reg] = mn;
                rstd2[i][reg] = rsqrtf(SS * (1.0f / C_) - mn * mn + 1e-5f);
            }
        #pragma unroll
        for (int j = 0; j < 4; ++j) {
            const int n = w * 64 + j * 16 + l16;
            const float wj = wB[n], bj = bB[n];
            #pragma unroll
            for (int i = 0; i < 2; ++i)
                #pragma unroll
                for (int reg = 0; reg < 4; ++reg) {
                    const float z = (acc[i][j][reg] - mean2[i][reg]) * rstd2[i][reg] * wj + bj;
                    out2[(size_t)(bm + i * 16 + q4 * 4 + reg) * C_ + n] = f2b(z);
                }
        }
    } else {
        #pragma unroll
        for (int i = 0; i < 2; ++i)
            #pragma unroll
            for (int reg = 0; reg < 4; ++reg) {
                const size_t ro = (size_t)(bm + i * 16 + q4 * 4 + reg) * C_;
                #pragma unroll
                for (int j = 0; j < 4; ++j) {
                    const int n = w * 64 + j * 16 + l16;
                    if constexpr (OB) out2[ro + n] = f2b(acc[i][j][reg]);
                    else              out1[ro + n] = acc[i][j][reg];
                }
            }
    }
}

// ---------------------------------------------------------------------------
// BARRIER-FREE causal flash attention, all operands register-resident.
// grid (32,H,B), 256 thr; wave w owns queries w*16..w*16+15 of a 64-q tile.
// K fragments double-buffered in registers (prefetch kb+1); V fragments
// loaded at tile start (latency hidden behind QK+softmax). ZERO LDS.
// Transposed scores -> P lands in mfma_16x16x16 A-operand layout; PV from
// registers. Constant-max softmax (exact).
// ---------------------------------------------------------------------------
__global__ __launch_bounds__(256) void attn_k(const u16* __restrict__ Q,
                                              const u16* __restrict__ K,
                                              const u16* __restrict__ Vt,
                                              u16* __restrict__ O)
{
    const int tid = threadIdx.x;
    const int lane = tid & 63, w = tid >> 6;
    const int q4 = lane >> 4, l16 = lane & 15;
    const int x = blockIdx.x, h = blockIdx.y, b = blockIdx.z;
    const int qb = (x & 1) ? 31 - (x >> 1) : (x >> 1);
    const size_t base  = ((size_t)b * S_) * C_ + h * D_;
    const size_t basev = ((size_t)(b * H_ + h)) * D_ * S_;

    s8v qf[2];
    #pragma unroll
    for (int kh = 0; kh < 2; ++kh)
        qf[kh] = *(const s8v*)&Q[base + (size_t)(qb * 64 + w * 16 + l16) * C_ + kh * 32 + q4 * 8];

    s8v kfA[2][4], kfB[2][4];
    s4v vb[4][4];

#define LOADK(KF, T) do {                                                       \
    _Pragma("unroll")                                                           \
    for (int kh = 0; kh < 2; ++kh)                                              \
        _Pragma("unroll")                                                       \
        for (int j = 0; j < 4; ++j)                                             \
            KF[kh][j] = *(const s8v*)&K[base + (size_t)((T) * 64 + j * 16 + l16) * C_ \
                                        + kh * 32 + q4 * 8];                    \
} while (0)

#define LOADV(T) do {                                                           \
    _Pragma("unroll")                                                           \
    for (int c = 0; c < 4; ++c)                                                 \
        _Pragma("unroll")                                                       \
        for (int dj = 0; dj < 4; ++dj)                                          \
            vb[c][dj] = *(const s4v*)&Vt[basev + (size_t)(dj * 16 + l16) * S_   \
                                         + (T) * 64 + c * 16 + q4 * 4];         \
} while (0)

    f4v o[4];
    float lp[4] = {0.f, 0.f, 0.f, 0.f};
    #pragma unroll
    for (int j = 0; j < 4; ++j) o[j] = (f4v){0.f, 0.f, 0.f, 0.f};
    const int qrow = w * 16 + l16;

#define PROC(KFC, KFN) do {                                                     \
    if (kb < qb) LOADK(KFN, kb + 1);                                            \
    LOADV(kb);                                                                  \
    f4v sc[4];                                                                  \
    _Pragma("unroll")                                                           \
    for (int j = 0; j < 4; ++j) sc[j] = (f4v){0.f, 0.f, 0.f, 0.f};              \
    _Pragma("unroll")                                                           \
    for (int kh = 0; kh < 2; ++kh)                                              \
        _Pragma("unroll")                                                       \
        for (int j = 0; j < 4; ++j)                                             \
            sc[j] = __builtin_amdgcn_mfma_f32_16x16x32_bf16(KFC[kh][j], qf[kh], sc[j], 0, 0, 0); \
    const bool diag = (kb == qb);                                               \
    s4v pa[4];                                                                  \
    _Pragma("unroll")                                                           \
    for (int j = 0; j < 4; ++j) {                                               \
        float ps = 0.0f;                                                        \
        _Pragma("unroll")                                                       \
        for (int reg = 0; reg < 4; ++reg) {                                     \
            float t = fmaf(sc[j][reg], 0.18033688011112043f, -11.541560327111707f); \
            if (diag && (j * 16 + q4 * 4 + reg) > qrow) t = -128.0f;            \
            const float p = exp2f(t);                                           \
            ps += p;                                                            \
            pa[j][reg] = (short)(__builtin_bit_cast(u32, p) >> 16);             \
        }                                                                       \
        lp[j] += ps;                                                            \
    }                                                                           \
    _Pragma("unroll")                                                           \
    for (int c = 0; c < 4; ++c)                                                 \
        _Pragma("unroll")                                                       \
        for (int dj = 0; dj < 4; ++dj)                                          \
            o[dj] = __builtin_amdgcn_mfma_f32_16x16x16bf16_1k(pa[c], vb[c][dj], o[dj], 0, 0, 0); \
} while (0)

    LOADK(kfA, 0);
    int kb = 0;
    for (;;) {
        PROC(kfA, kfB);
        if (kb == qb) break;
        ++kb;
        PROC(kfB, kfA);
        if (kb == qb) break;
        ++kb;
    }
#undef PROC
#undef LOADK
#undef LOADV

    float lt = (lp[0] + lp[1]) + (lp[2] + lp[3]);
    lt += __shfl_xor(lt, 16);
    lt += __shfl_xor(lt, 32);
    #pragma unroll
    for (int reg = 0; reg < 4; ++reg) {
        const float inv = 1.0f / __shfl(lt, q4 * 4 + reg);
        const size_t rowoff = base + (size_t)(qb * 64 + w * 16 + q4 * 4 + reg) * C_;
        #pragma unroll
        for (int dj = 0; dj < 4; ++dj)
            O[rowoff + dj * 16 + l16] = f2b(o[dj][reg] * inv);
    }
}

// ---------------------------------------------------------------------------
extern "C" void kernel_launch(void* const* d_in, const int* in_sizes, int n_in,
                              void* d_out, int out_size, void* d_ws, size_t ws_size,
                              hipStream_t stream)
{
    const float* x       = (const float*)d_in[0];
    const float* Wq      = (const float*)d_in[1];
    const float* Wk      = (const float*)d_in[2];
    const float* Wv      = (const float*)d_in[3];
    const float* Wo      = (const float*)d_in[4];
    const float* ln1_w   = (const float*)d_in[5];
    const float* ln1_b   = (const float*)d_in[6];
    const float* ffln1_w = (const float*)d_in[7];
    const float* ffln1_b = (const float*)d_in[8];
    const float* ff_w1   = (const float*)d_in[9];
    const float* ff_b1   = (const float*)d_in[10];
    const float* ffln2_w = (const float*)d_in[11];
    const float* ffln2_b = (const float*)d_in[12];
    const float* ff_w2   = (const float*)d_in[13];
    const float* ff_b2   = (const float*)d_in[14];
    const float* ln2_w   = (const float*)d_in[15];
    const float* ln2_b   = (const float*)d_in[16];
    float* out = (float*)d_out;

    const size_t MC = (size_t)M_ * C_;   // 4,194,304
    const size_t WW = (size_t)C_ * C_;
    u16* xb   = (u16*)d_ws;
    u16* WqT  = xb + MC;
    u16* WkT  = WqT + WW;
    u16* WvT  = WkT + WW;
    u16* WoT  = WvT + WW;
    u16* W1T  = WoT + WW;
    u16* W2T  = W1T + WW;
    u16* qbuf = W2T + WW;
    u16* kbuf = qbuf + MC;
    u16* vtbuf= kbuf + MC;
    u16*  abuf = xb;              // attn out; xb dead after qkv_k
    float* xln = (float*)qbuf;    // fp32 overlays qbuf+kbuf (dead after attn)

    const dim3 gq(12, M_ / 128);         // fused QKV
    const dim3 ga(32, H_, B_);           // 1024 attn blocks (64-query tiles)
    const dim3 gt(16, 16, 6);            // all 6 weight transposes
    const int  gf = M_ / 32;             // 256 fused-GEMM blocks

    conv_k<<<MC / 1024, 256, 0, stream>>>(x, xb);
    trconv6_k<<<gt, 256, 0, stream>>>(Wq, Wk, Wv, Wo, ff_w1, ff_w2,
                                      WqT, WkT, WvT, WoT, W1T, W2T);

    qkv_k<<<gq, 256, 0, stream>>>(xb, WqT, WkT, WvT, qbuf, kbuf, vtbuf);
    attn_k<<<ga, 256, 0, stream>>>(qbuf, kbuf, vtbuf, abuf);

    // t = a@Wo; xln = LN(t+x, ln1); xb(bf16) = LN(xln, ffln1)
    fgemm_k<false, true, true, true><<<gf, 512, 0, stream>>>(
        abuf, WoT, nullptr, x, ln1_w, ln1_b, ffln1_w, ffln1_b, xln, xb);
    // h1 = xb@W1 + b1; xb(bf16) = LN(h1, ffln2)
    fgemm_k<true, false, false, true><<<gf, 512, 0, stream>>>(
        xb, W1T, ff_b1, nullptr, ffln2_w, ffln2_b, nullptr, nullptr, nullptr, xb);
    // h2 = xb@W2 + b2; out(fp32) = LN(h2 + xln, ln2)
    fgemm_k<true, true, false, false><<<gf, 512, 0, stream>>>(
        xb, W2T, ff_b2, xln, ln2_w, ln2_b, nullptr, nullptr, out, nullptr);
}

// Round 9
// 267.615 us; speedup vs baseline: 2.1051x; 2.1051x over previous
//
#include <hip/hip_runtime.h>

#define B_ 4
#define S_ 2048
#define C_ 512
#define H_ 8
#define D_ 64
#define M_ 8192   // B_*S_

typedef short s8v __attribute__((ext_vector_type(8)));   // 8 bf16 (4 VGPRs)
typedef short s4v __attribute__((ext_vector_type(4)));   // 4 bf16 (2 VGPRs)
typedef float f4v __attribute__((ext_vector_type(4)));   // MFMA C/D
typedef unsigned short u16;
typedef unsigned int u32;

__device__ __forceinline__ u16 f2b(float f) {
    u32 u = __builtin_bit_cast(u32, f);
    u = u + 0x7fffu + ((u >> 16) & 1u);
    return (u16)(u >> 16);
}

// async 16B global->LDS; lds dest is wave-uniform base, lane i lands at +16*i
__device__ __forceinline__ void gl2lds16(const void* g, void* l) {
    __builtin_amdgcn_global_load_lds(
        (const __attribute__((address_space(1))) void*)g,
        (__attribute__((address_space(3))) void*)l, 16, 0, 0);
}

// ---------------------------------------------------------------------------
__global__ __launch_bounds__(256) void conv_k(const float* __restrict__ s,
                                              u16* __restrict__ d) {
    const int i = (blockIdx.x * 256 + threadIdx.x) * 4;
    const float4 v = *(const float4*)&s[i];
    ushort4 o;
    o.x = f2b(v.x); o.y = f2b(v.y); o.z = f2b(v.z); o.w = f2b(v.w);
    *(ushort4*)&d[i] = o;
}

// ---------------------------------------------------------------------------
// All six weight transposes in ONE launch: blockIdx.z selects the matrix.
// ---------------------------------------------------------------------------
__global__ __launch_bounds__(256) void trconv6_k(const float* __restrict__ s0,
                                                 const float* __restrict__ s1,
                                                 const float* __restrict__ s2,
                                                 const float* __restrict__ s3,
                                                 const float* __restrict__ s4,
                                                 const float* __restrict__ s5,
                                                 u16* __restrict__ d0,
                                                 u16* __restrict__ d1,
                                                 u16* __restrict__ d2,
                                                 u16* __restrict__ d3,
                                                 u16* __restrict__ d4,
                                                 u16* __restrict__ d5)
{
    const float* W; u16* Wt;
    switch (blockIdx.z) {
        case 0: W = s0; Wt = d0; break;
        case 1: W = s1; Wt = d1; break;
        case 2: W = s2; Wt = d2; break;
        case 3: W = s3; Wt = d3; break;
        case 4: W = s4; Wt = d4; break;
        default: W = s5; Wt = d5; break;
    }
    __shared__ float t[32][33];
    const int tx = threadIdx.x & 31, ty = threadIdx.x >> 5;
    const int n0 = blockIdx.x * 32, k0 = blockIdx.y * 32;
    #pragma unroll
    for (int i = 0; i < 4; ++i)
        t[ty + i * 8][tx] = W[(size_t)(k0 + ty + i * 8) * C_ + n0 + tx];
    __syncthreads();
    #pragma unroll
    for (int i = 0; i < 4; ++i)
        Wt[(size_t)(n0 + ty + i * 8) * C_ + k0 + tx] = f2b(t[tx][ty + i * 8]);
}

// ---------------------------------------------------------------------------
// bf16 MFMA GEMM, 64x64 tile (grid (8,128) = 1024 blocks -> 4/CU), BK=32,
// double-buffered LDS (16 KB), one barrier/iter. 4 waves, each 32x32.
// ---------------------------------------------------------------------------
template <bool OB>
__global__ __launch_bounds__(256) void gemm_k(const u16* __restrict__ A,
                                              const u16* __restrict__ Bt,
                                              const float* __restrict__ bias,
                                              void* __restrict__ outv)
{
    __shared__ u16 As[2][4][16][32];   // 4KB/buf
    __shared__ u16 Bs[2][4][16][32];
    const int tid = threadIdx.x;
    const int lane = tid & 63, w = tid >> 6;
    const int q4 = lane >> 4, l16 = lane & 15;
    const int wr = w >> 1, wc = w & 1;
    const int bm = blockIdx.y * 64, bn = blockIdx.x * 64;
    const int lr = lane >> 2, lc = (lane & 3) * 8;

    f4v acc[2][2];
    #pragma unroll
    for (int i = 0; i < 2; ++i)
        #pragma unroll
        for (int j = 0; j < 2; ++j) acc[i][j] = (f4v){0.f, 0.f, 0.f, 0.f};

    gl2lds16(A  + (size_t)(bm + w * 16 + lr) * C_ + lc, (char*)As + w * 1024);
    gl2lds16(Bt + (size_t)(bn + w * 16 + lr) * C_ + lc, (char*)Bs + w * 1024);

    for (int kt = 0; kt < 16; ++kt) {
        __syncthreads();
        const int buf = kt & 1;
        if (kt < 15) {
            const int nb = buf ^ 1, k0 = (kt + 1) * 32;
            gl2lds16(A  + (size_t)(bm + w * 16 + lr) * C_ + k0 + lc,
                     (char*)As + nb * 4096 + w * 1024);
            gl2lds16(Bt + (size_t)(bn + w * 16 + lr) * C_ + k0 + lc,
                     (char*)Bs + nb * 4096 + w * 1024);
        }
        s8v a[2], bfr[2];
        #pragma unroll
        for (int i = 0; i < 2; ++i) {
            const int row = wr * 32 + i * 16 + l16;
            a[i] = *(const s8v*)&As[buf][row >> 4][row & 15][q4 * 8];
        }
        #pragma unroll
        for (int j = 0; j < 2; ++j) {
            const int row = wc * 32 + j * 16 + l16;
            bfr[j] = *(const s8v*)&Bs[buf][row >> 4][row & 15][q4 * 8];
        }
        #pragma unroll
        for (int i = 0; i < 2; ++i)
            #pragma unroll
            for (int j = 0; j < 2; ++j)
                acc[i][j] = __builtin_amdgcn_mfma_f32_16x16x32_bf16(a[i], bfr[j], acc[i][j], 0, 0, 0);
    }

    #pragma unroll
    for (int j = 0; j < 2; ++j) {
        const int n = bn + wc * 32 + j * 16 + l16;
        const float bj = bias ? bias[n] : 0.0f;
        #pragma unroll
        for (int i = 0; i < 2; ++i) {
            const int m = bm + wr * 32 + i * 16 + q4 * 4;
            #pragma unroll
            for (int reg = 0; reg < 4; ++reg) {
                const float vv = acc[i][j][reg] + bj;
                if constexpr (OB) ((u16*)outv)[(size_t)(m + reg) * C_ + n] = f2b(vv);
                else              ((float*)outv)[(size_t)(m + reg) * C_ + n] = vv;
            }
        }
    }
}

// ---------------------------------------------------------------------------
// Fused QKV projection, 64x64 tiles, grid (24, 128) = 3072 blocks (~8/CU).
// which = nt>>3 selects {Wq,Wk,Wv}; V written TRANSPOSED + XOR-swizzled
// into Vt[b,h,d,s]: within each 32-key span, 4-key group g -> g ^ (d&7).
// ---------------------------------------------------------------------------
__global__ __launch_bounds__(256) void qkv_k(const u16* __restrict__ A,
                                             const u16* __restrict__ Wq,
                                             const u16* __restrict__ Wk,
                                             const u16* __restrict__ Wv,
                                             u16* __restrict__ oq,
                                             u16* __restrict__ ok,
                                             u16* __restrict__ ovt)
{
    __shared__ u16 As[2][4][16][32];
    __shared__ u16 Bs[2][4][16][32];
    const int tid = threadIdx.x;
    const int lane = tid & 63, w = tid >> 6;
    const int q4 = lane >> 4, l16 = lane & 15;
    const int wr = w >> 1, wc = w & 1;
    const int nt = blockIdx.x, which = nt >> 3;
    const u16* Bt = which == 0 ? Wq : (which == 1 ? Wk : Wv);
    const int bm = blockIdx.y * 64, bn = (nt & 7) * 64;
    const int lr = lane >> 2, lc = (lane & 3) * 8;

    f4v acc[2][2];
    #pragma unroll
    for (int i = 0; i < 2; ++i)
        #pragma unroll
        for (int j = 0; j < 2; ++j) acc[i][j] = (f4v){0.f, 0.f, 0.f, 0.f};

    gl2lds16(A  + (size_t)(bm + w * 16 + lr) * C_ + lc, (char*)As + w * 1024);
    gl2lds16(Bt + (size_t)(bn + w * 16 + lr) * C_ + lc, (char*)Bs + w * 1024);

    for (int kt = 0; kt < 16; ++kt) {
        __syncthreads();
        const int buf = kt & 1;
        if (kt < 15) {
            const int nb = buf ^ 1, k0 = (kt + 1) * 32;
            gl2lds16(A  + (size_t)(bm + w * 16 + lr) * C_ + k0 + lc,
                     (char*)As + nb * 4096 + w * 1024);
            gl2lds16(Bt + (size_t)(bn + w * 16 + lr) * C_ + k0 + lc,
                     (char*)Bs + nb * 4096 + w * 1024);
        }
        s8v a[2], bfr[2];
        #pragma unroll
        for (int i = 0; i < 2; ++i) {
            const int row = wr * 32 + i * 16 + l16;
            a[i] = *(const s8v*)&As[buf][row >> 4][row & 15][q4 * 8];
        }
        #pragma unroll
        for (int j = 0; j < 2; ++j) {
            const int row = wc * 32 + j * 16 + l16;
            bfr[j] = *(const s8v*)&Bs[buf][row >> 4][row & 15][q4 * 8];
        }
        #pragma unroll
        for (int i = 0; i < 2; ++i)
            #pragma unroll
            for (int j = 0; j < 2; ++j)
                acc[i][j] = __builtin_amdgcn_mfma_f32_16x16x32_bf16(a[i], bfr[j], acc[i][j], 0, 0, 0);
    }

    if (which != 2) {
        u16* outp = which == 0 ? oq : ok;
        #pragma unroll
        for (int j = 0; j < 2; ++j) {
            const int n = bn + wc * 32 + j * 16 + l16;
            #pragma unroll
            for (int i = 0; i < 2; ++i) {
                const int m = bm + wr * 32 + i * 16 + q4 * 4;
                #pragma unroll
                for (int reg = 0; reg < 4; ++reg)
                    outp[(size_t)(m + reg) * C_ + n] = f2b(acc[i][j][reg]);
            }
        }
    } else {
        // V: transposed + swizzled write. m -> s, n -> (h,d).
        const int bglob = bm >> 11;
        const int sbase = bm & (S_ - 1);
        #pragma unroll
        for (int j = 0; j < 2; ++j) {
            const int n = bn + wc * 32 + j * 16 + l16;
            const int h = n >> 6, d = n & 63;
            u16* vrow = ovt + ((size_t)(bglob * H_ + h) * D_ + d) * S_;
            const int xw = d & 7;
            #pragma unroll
            for (int i = 0; i < 2; ++i) {
                const int s = sbase + wr * 32 + i * 16 + q4 * 4;
                const int pg = ((s & 31) >> 2) ^ xw;
                s4v pv;
                #pragma unroll
                for (int reg = 0; reg < 4; ++reg) pv[reg] = (short)f2b(acc[i][j][reg]);
                *(s4v*)&vrow[(s & ~31) + (pg << 2)] = pv;
            }
        }
    }
}

// ---------------------------------------------------------------------------
// LayerNorm (512), fp32 in (+opt residual), fp32/bf16 out. 4 rows/block.
// ---------------------------------------------------------------------------
template <bool OB>
__global__ __launch_bounds__(256) void ln_k(const float* __restrict__ in,
                                            const float* __restrict__ res,
                                            const float* __restrict__ w,
                                            const float* __restrict__ bb,
                                            void* __restrict__ outv)
{
    const int lane = threadIdx.x & 63;
    const int row  = blockIdx.x * 4 + (threadIdx.x >> 6);
    const float* p = in + (size_t)row * C_;
    float4 v0 = *(const float4*)&p[lane * 4];
    float4 v1 = *(const float4*)&p[256 + lane * 4];
    if (res) {
        const float* rp = res + (size_t)row * C_;
        const float4 r0 = *(const float4*)&rp[lane * 4];
        const float4 r1 = *(const float4*)&rp[256 + lane * 4];
        v0.x += r0.x; v0.y += r0.y; v0.z += r0.z; v0.w += r0.w;
        v1.x += r1.x; v1.y += r1.y; v1.z += r1.z; v1.w += r1.w;
    }
    float s  = v0.x + v0.y + v0.z + v0.w + v1.x + v1.y + v1.z + v1.w;
    float ss = v0.x*v0.x + v0.y*v0.y + v0.z*v0.z + v0.w*v0.w
             + v1.x*v1.x + v1.y*v1.y + v1.z*v1.z + v1.w*v1.w;
    #pragma unroll
    for (int off = 32; off >= 1; off >>= 1) {
        s  += __shfl_xor(s, off);
        ss += __shfl_xor(ss, off);
    }
    const float mean = s * (1.0f / C_);
    const float var  = ss * (1.0f / C_) - mean * mean;
    const float rstd = rsqrtf(var + 1e-5f);

    const float4 w0 = *(const float4*)&w[lane * 4];
    const float4 w1 = *(const float4*)&w[256 + lane * 4];
    const float4 b0 = *(const float4*)&bb[lane * 4];
    const float4 b1 = *(const float4*)&bb[256 + lane * 4];
    float4 o0, o1;
    o0.x = (v0.x - mean) * rstd * w0.x + b0.x;
    o0.y = (v0.y - mean) * rstd * w0.y + b0.y;
    o0.z = (v0.z - mean) * rstd * w0.z + b0.z;
    o0.w = (v0.w - mean) * rstd * w0.w + b0.w;
    o1.x = (v1.x - mean) * rstd * w1.x + b1.x;
    o1.y = (v1.y - mean) * rstd * w1.y + b1.y;
    o1.z = (v1.z - mean) * rstd * w1.z + b1.z;
    o1.w = (v1.w - mean) * rstd * w1.w + b1.w;
    if constexpr (OB) {
        u16* op = (u16*)outv + (size_t)row * C_;
        ushort4 u0, u1;
        u0.x = f2b(o0.x); u0.y = f2b(o0.y); u0.z = f2b(o0.z); u0.w = f2b(o0.w);
        u1.x = f2b(o1.x); u1.y = f2b(o1.y); u1.z = f2b(o1.z); u1.w = f2b(o1.w);
        *(ushort4*)&op[lane * 4]       = u0;
        *(ushort4*)&op[256 + lane * 4] = u1;
    } else {
        float* op = (float*)outv + (size_t)row * C_;
        *(float4*)&op[lane * 4]       = o0;
        *(float4*)&op[256 + lane * 4] = o1;
    }
}

// ---------------------------------------------------------------------------
// Fused double-LayerNorm: y1 = LN(in+res)*w1+b1 (fp32 -> out1),
// y2 = LN(y1)*w2+b2 (bf16 -> out2). One wave per row, 4 rows/block.
// ---------------------------------------------------------------------------
__global__ __launch_bounds__(256) void ln2x_k(const float* __restrict__ in,
                                              const float* __restrict__ res,
                                              const float* __restrict__ w1,
                                              const float* __restrict__ b1,
                                              const float* __restrict__ w2,
                                              const float* __restrict__ b2,
                                              float* __restrict__ out1,
                                              u16* __restrict__ out2)
{
    const int lane = threadIdx.x & 63;
    const int row  = blockIdx.x * 4 + (threadIdx.x >> 6);
    const float* p  = in  + (size_t)row * C_;
    const float* rp = res + (size_t)row * C_;
    float4 v0 = *(const float4*)&p[lane * 4];
    float4 v1 = *(const float4*)&p[256 + lane * 4];
    {
        const float4 r0 = *(const float4*)&rp[lane * 4];
        const float4 r1 = *(const float4*)&rp[256 + lane * 4];
        v0.x += r0.x; v0.y += r0.y; v0.z += r0.z; v0.w += r0.w;
        v1.x += r1.x; v1.y += r1.y; v1.z += r1.z; v1.w += r1.w;
    }
    float s  = v0.x + v0.y + v0.z + v0.w + v1.x + v1.y + v1.z + v1.w;
    float ss = v0.x*v0.x + v0.y*v0.y + v0.z*v0.z + v0.w*v0.w
             + v1.x*v1.x + v1.y*v1.y + v1.z*v1.z + v1.w*v1.w;
    #pragma unroll
    for (int off = 32; off >= 1; off >>= 1) {
        s  += __shfl_xor(s, off);
        ss += __shfl_xor(ss, off);
    }
    float mean = s * (1.0f / C_);
    float var  = ss * (1.0f / C_) - mean * mean;
    float rstd = rsqrtf(var + 1e-5f);

    const float4 wA0 = *(const float4*)&w1[lane * 4];
    const float4 wA1 = *(const float4*)&w1[256 + lane * 4];
    const float4 bA0 = *(const float4*)&b1[lane * 4];
    const float4 bA1 = *(const float4*)&b1[256 + lane * 4];
    float4 y0, y1v;
    y0.x  = (v0.x - mean) * rstd * wA0.x + bA0.x;
    y0.y  = (v0.y - mean) * rstd * wA0.y + bA0.y;
    y0.z  = (v0.z - mean) * rstd * wA0.z + bA0.z;
    y0.w  = (v0.w - mean) * rstd * wA0.w + bA0.w;
    y1v.x = (v1.x - mean) * rstd * wA1.x + bA1.x;
    y1v.y = (v1.y - mean) * rstd * wA1.y + bA1.y;
    y1v.z = (v1.z - mean) * rstd * wA1.z + bA1.z;
    y1v.w = (v1.w - mean) * rstd * wA1.w + bA1.w;
    float* op1 = out1 + (size_t)row * C_;
    *(float4*)&op1[lane * 4]       = y0;
    *(float4*)&op1[256 + lane * 4] = y1v;

    s  = y0.x + y0.y + y0.z + y0.w + y1v.x + y1v.y + y1v.z + y1v.w;
    ss = y0.x*y0.x + y0.y*y0.y + y0.z*y0.z + y0.w*y0.w
       + y1v.x*y1v.x + y1v.y*y1v.y + y1v.z*y1v.z + y1v.w*y1v.w;
    #pragma unroll
    for (int off = 32; off >= 1; off >>= 1) {
        s  += __shfl_xor(s, off);
        ss += __shfl_xor(ss, off);
    }
    mean = s * (1.0f / C_);
    var  = ss * (1.0f / C_) - mean * mean;
    rstd = rsqrtf(var + 1e-5f);

    const float4 wB0 = *(const float4*)&w2[lane * 4];
    const float4 wB1 = *(const float4*)&w2[256 + lane * 4];
    const float4 bB0 = *(const float4*)&b2[lane * 4];
    const float4 bB1 = *(const float4*)&b2[256 + lane * 4];
    ushort4 u0, u1;
    u0.x = f2b((y0.x - mean) * rstd * wB0.x + bB0.x);
    u0.y = f2b((y0.y - mean) * rstd * wB0.y + bB0.y);
    u0.z = f2b((y0.z - mean) * rstd * wB0.z + bB0.z);
    u0.w = f2b((y0.w - mean) * rstd * wB0.w + bB0.w);
    u1.x = f2b((y1v.x - mean) * rstd * wB1.x + bB1.x);
    u1.y = f2b((y1v.y - mean) * rstd * wB1.y + bB1.y);
    u1.z = f2b((y1v.z - mean) * rstd * wB1.z + bB1.z);
    u1.w = f2b((y1v.w - mean) * rstd * wB1.w + bB1.w);
    u16* op2 = out2 + (size_t)row * C_;
    *(ushort4*)&op2[lane * 4]       = u0;
    *(ushort4*)&op2[256 + lane * 4] = u1;
}

// ---------------------------------------------------------------------------
// Causal flash attention, register-resident P (round-5/7 version). grid
// (32,H,B), 256 thr; wave w owns queries w*16..w*16+15 of a 64-query tile.
// Transposed scores -> lane holds P in mfma_16x16x16 A-operand layout; PV
// straight from registers. Constant-max softmax (exact). K/V^T double-
// buffered via global_load_lds; 32 KB LDS, VGPR ~48.
// ---------------------------------------------------------------------------
__global__ __launch_bounds__(256) void attn_k(const u16* __restrict__ Q,
                                              const u16* __restrict__ K,
                                              const u16* __restrict__ Vt,
                                              u16* __restrict__ O)
{
    __shared__ u16 Ks[2][2][64][32];   // [buf][kh][key][k32]   8KB/buf
    __shared__ u16 Vs[2][2][64][32];   // [buf][keyhalf][d][key32] (swizzled)
    const int tid = threadIdx.x;
    const int lane = tid & 63, w = tid >> 6;
    const int q4 = lane >> 4, l16 = lane & 15;
    const int x = blockIdx.x, h = blockIdx.y, b = blockIdx.z;
    const int qb = (x & 1) ? 31 - (x >> 1) : (x >> 1);
    const size_t base  = ((size_t)b * S_) * C_ + h * D_;
    const size_t basev = ((size_t)(b * H_ + h)) * D_ * S_;
    const int lr = lane >> 2, lc = (lane & 3) * 8;

    s8v qf[2];
    #pragma unroll
    for (int kh = 0; kh < 2; ++kh)
        qf[kh] = *(const s8v*)&Q[base + (size_t)(qb * 64 + w * 16 + l16) * C_ + kh * 32 + q4 * 8];

    #pragma unroll
    for (int r = 0; r < 2; ++r) {
        const int seg = r * 4 + w;
        const int row = (seg & 3) * 16 + lr;
        const int kh = seg >> 2;
        gl2lds16(K  + base  + (size_t)row * C_ + kh * 32 + lc, (char*)Ks + seg * 1024);
        gl2lds16(Vt + basev + (size_t)row * S_ + kh * 32 + lc, (char*)Vs + seg * 1024);
    }

    f4v o[4];
    float lp[4] = {0.f, 0.f, 0.f, 0.f};
    #pragma unroll
    for (int j = 0; j < 4; ++j) o[j] = (f4v){0.f, 0.f, 0.f, 0.f};

    const int qrow = w * 16 + l16;
    for (int kb = 0; kb <= qb; ++kb) {
        __syncthreads();
        const int buf = kb & 1;
        if (kb < qb) {
            const int nb = buf ^ 1, kn = kb + 1;
            #pragma unroll
            for (int r = 0; r < 2; ++r) {
                const int seg = r * 4 + w;
                const int row = (seg & 3) * 16 + lr;
                const int kh = seg >> 2;
                gl2lds16(K  + base  + (size_t)(kn * 64 + row) * C_ + kh * 32 + lc,
                         (char*)Ks + nb * 8192 + seg * 1024);
                gl2lds16(Vt + basev + (size_t)row * S_ + kn * 64 + kh * 32 + lc,
                         (char*)Vs + nb * 8192 + seg * 1024);
            }
        }

        f4v sc[4];
        #pragma unroll
        for (int j = 0; j < 4; ++j) sc[j] = (f4v){0.f, 0.f, 0.f, 0.f};
        #pragma unroll
        for (int kh = 0; kh < 2; ++kh) {
            #pragma unroll
            for (int j = 0; j < 4; ++j) {
                const s8v kf = *(const s8v*)&Ks[buf][kh][j * 16 + l16][q4 * 8];
                sc[j] = __builtin_amdgcn_mfma_f32_16x16x32_bf16(kf, qf[kh], sc[j], 0, 0, 0);
            }
        }

        const bool diag = (kb == qb);
        s4v pa[4];
        #pragma unroll
        for (int j = 0; j < 4; ++j) {
            float ps = 0.0f;
            #pragma unroll
            for (int reg = 0; reg < 4; ++reg) {
                float t = fmaf(sc[j][reg], 0.18033688011112043f, -11.541560327111707f);
                if (diag && (j * 16 + q4 * 4 + reg) > qrow) t = -128.0f;
                const float p = exp2f(t);
                ps += p;
                pa[j][reg] = (short)(__builtin_bit_cast(u32, p) >> 16);
            }
            lp[j] += ps;
        }

        #pragma unroll
        for (int c = 0; c < 4; ++c) {
            const int gh = (((c & 1) * 4 + q4) ^ (l16 & 7)) * 4;
            #pragma unroll
            for (int dj = 0; dj < 4; ++dj) {
                const s4v vb = *(const s4v*)&Vs[buf][c >> 1][dj * 16 + l16][gh];
                o[dj] = __builtin_amdgcn_mfma_f32_16x16x16bf16_1k(pa[c], vb, o[dj], 0, 0, 0);
            }
        }
    }

    float lt = (lp[0] + lp[1]) + (lp[2] + lp[3]);
    lt += __shfl_xor(lt, 16);
    lt += __shfl_xor(lt, 32);
    #pragma unroll
    for (int reg = 0; reg < 4; ++reg) {
        const float inv = 1.0f / __shfl(lt, q4 * 4 + reg);
        const size_t rowoff = base + (size_t)(qb * 64 + w * 16 + q4 * 4 + reg) * C_;
        #pragma unroll
        for (int dj = 0; dj < 4; ++dj)
            O[rowoff + dj * 16 + l16] = f2b(o[dj][reg] * inv);
    }
}

// ---------------------------------------------------------------------------
extern "C" void kernel_launch(void* const* d_in, const int* in_sizes, int n_in,
                              void* d_out, int out_size, void* d_ws, size_t ws_size,
                              hipStream_t stream)
{
    const float* x       = (const float*)d_in[0];
    const float* Wq      = (const float*)d_in[1];
    const float* Wk      = (const float*)d_in[2];
    const float* Wv      = (const float*)d_in[3];
    const float* Wo      = (const float*)d_in[4];
    const float* ln1_w   = (const float*)d_in[5];
    const float* ln1_b   = (const float*)d_in[6];
    const float* ffln1_w = (const float*)d_in[7];
    const float* ffln1_b = (const float*)d_in[8];
    const float* ff_w1   = (const float*)d_in[9];
    const float* ff_b1   = (const float*)d_in[10];
    const float* ffln2_w = (const float*)d_in[11];
    const float* ffln2_b = (const float*)d_in[12];
    const float* ff_w2   = (const float*)d_in[13];
    const float* ff_b2   = (const float*)d_in[14];
    const float* ln2_w   = (const float*)d_in[15];
    const float* ln2_b   = (const float*)d_in[16];
    float* out = (float*)d_out;

    const size_t MC = (size_t)M_ * C_;   // 4,194,304
    const size_t WW = (size_t)C_ * C_;
    u16* xb   = (u16*)d_ws;
    u16* WqT  = xb + MC;
    u16* WkT  = WqT + WW;
    u16* WvT  = WkT + WW;
    u16* WoT  = WvT + WW;
    u16* W1T  = WoT + WW;
    u16* W2T  = W1T + WW;
    u16* qbuf = W2T + WW;
    u16* kbuf = qbuf + MC;
    u16* vbuf = kbuf + MC;     // spare MC (xln overlay)
    u16* vtbuf= vbuf + MC;
    u16*  abuf = xb;              // attn out; xb dead after qkv_k
    float* tf  = (float*)qbuf;    // fp32 overlays qbuf+kbuf (dead after attn)
    float* xln = (float*)vbuf;    // fp32 overlays vbuf+vtbuf (dead after attn)

    const dim3 gg(C_ / 64, M_ / 64);     // (8, 128) = 1024 gemm blocks
    const dim3 gq(24, M_ / 64);          // fused QKV, 3072 blocks
    const dim3 ga(32, H_, B_);           // 1024 attn blocks (64-query tiles)
    const dim3 gt(16, 16, 6);            // all 6 weight transposes
    const int  gl = M_ / 4;

    conv_k<<<MC / 1024, 256, 0, stream>>>(x, xb);
    trconv6_k<<<gt, 256, 0, stream>>>(Wq, Wk, Wv, Wo, ff_w1, ff_w2,
                                      WqT, WkT, WvT, WoT, W1T, W2T);

    qkv_k<<<gq, 256, 0, stream>>>(xb, WqT, WkT, WvT, qbuf, kbuf, vtbuf);
    attn_k<<<ga, 256, 0, stream>>>(qbuf, kbuf, vtbuf, abuf);

    // t = a@Wo -> tf; xln = LN(t+x, ln1); xb(bf16) = LN(xln, ffln1)
    gemm_k<false><<<gg, 256, 0, stream>>>(abuf, WoT, nullptr, tf);
    ln2x_k<<<gl, 256, 0, stream>>>(tf, x, ln1_w, ln1_b, ffln1_w, ffln1_b,
                                   xln, xb);
    // h1 = xb@W1 + b1 -> tf; xb(bf16) = LN(h1, ffln2)
    gemm_k<false><<<gg, 256, 0, stream>>>(xb, W1T, ff_b1, tf);
    ln_k<true><<<gl, 256, 0, stream>>>(tf, nullptr, ffln2_w, ffln2_b, xb);
    // h2 = xb@W2 + b2 -> tf; out = LN(h2 + xln, ln2)
    gemm_k<false><<<gg, 256, 0, stream>>>(xb, W2T, ff_b2, tf);
    ln_k<false><<<gl, 256, 0, stream>>>(tf, xln, ln2_w, ln2_b, out);
}

// Round 10
// 263.493 us; speedup vs baseline: 2.1381x; 1.0156x over previous
//
#include <hip/hip_runtime.h>

#define B_ 4
#define S_ 2048
#define C_ 512
#define H_ 8
#define D_ 64
#define M_ 8192   // B_*S_

typedef short s8v __attribute__((ext_vector_type(8)));   // 8 bf16 (4 VGPRs)
typedef short s4v __attribute__((ext_vector_type(4)));   // 4 bf16 (2 VGPRs)
typedef float f4v __attribute__((ext_vector_type(4)));   // MFMA C/D
typedef unsigned short u16;
typedef unsigned int u32;

__device__ __forceinline__ u16 f2b(float f) {
    u32 u = __builtin_bit_cast(u32, f);
    u = u + 0x7fffu + ((u >> 16) & 1u);
    return (u16)(u >> 16);
}

__device__ __forceinline__ void b2f8(const s8v v, float* f) {
    #pragma unroll
    for (int k = 0; k < 8; ++k)
        f[k] = __builtin_bit_cast(float, (u32)(u16)v[k] << 16);
}

// async 16B global->LDS; lds dest is wave-uniform base, lane i lands at +16*i
__device__ __forceinline__ void gl2lds16(const void* g, void* l) {
    __builtin_amdgcn_global_load_lds(
        (const __attribute__((address_space(1))) void*)g,
        (__attribute__((address_space(3))) void*)l, 16, 0, 0);
}

// ---------------------------------------------------------------------------
__global__ __launch_bounds__(256) void conv_k(const float* __restrict__ s,
                                              u16* __restrict__ d) {
    const int i = (blockIdx.x * 256 + threadIdx.x) * 4;
    const float4 v = *(const float4*)&s[i];
    ushort4 o;
    o.x = f2b(v.x); o.y = f2b(v.y); o.z = f2b(v.z); o.w = f2b(v.w);
    *(ushort4*)&d[i] = o;
}

// ---------------------------------------------------------------------------
// All six weight transposes in ONE launch: blockIdx.z selects the matrix.
// ---------------------------------------------------------------------------
__global__ __launch_bounds__(256) void trconv6_k(const float* __restrict__ s0,
                                                 const float* __restrict__ s1,
                                                 const float* __restrict__ s2,
                                                 const float* __restrict__ s3,
                                                 const float* __restrict__ s4,
                                                 const float* __restrict__ s5,
                                                 u16* __restrict__ d0,
                                                 u16* __restrict__ d1,
                                                 u16* __restrict__ d2,
                                                 u16* __restrict__ d3,
                                                 u16* __restrict__ d4,
                                                 u16* __restrict__ d5)
{
    const float* W; u16* Wt;
    switch (blockIdx.z) {
        case 0: W = s0; Wt = d0; break;
        case 1: W = s1; Wt = d1; break;
        case 2: W = s2; Wt = d2; break;
        case 3: W = s3; Wt = d3; break;
        case 4: W = s4; Wt = d4; break;
        default: W = s5; Wt = d5; break;
    }
    __shared__ float t[32][33];
    const int tx = threadIdx.x & 31, ty = threadIdx.x >> 5;
    const int n0 = blockIdx.x * 32, k0 = blockIdx.y * 32;
    #pragma unroll
    for (int i = 0; i < 4; ++i)
        t[ty + i * 8][tx] = W[(size_t)(k0 + ty + i * 8) * C_ + n0 + tx];
    __syncthreads();
    #pragma unroll
    for (int i = 0; i < 4; ++i)
        Wt[(size_t)(n0 + ty + i * 8) * C_ + k0 + tx] = f2b(t[tx][ty + i * 8]);
}

// ---------------------------------------------------------------------------
// bf16 MFMA GEMM, 64x64 tile (1024 blocks -> 4/CU), BK=32, double-buffered.
// ---------------------------------------------------------------------------
template <bool OB>
__global__ __launch_bounds__(256) void gemm_k(const u16* __restrict__ A,
                                              const u16* __restrict__ Bt,
                                              const float* __restrict__ bias,
                                              void* __restrict__ outv)
{
    __shared__ u16 As[2][4][16][32];   // 4KB/buf
    __shared__ u16 Bs[2][4][16][32];
    const int tid = threadIdx.x;
    const int lane = tid & 63, w = tid >> 6;
    const int q4 = lane >> 4, l16 = lane & 15;
    const int wr = w >> 1, wc = w & 1;
    const int bm = blockIdx.y * 64, bn = blockIdx.x * 64;
    const int lr = lane >> 2, lc = (lane & 3) * 8;

    f4v acc[2][2];
    #pragma unroll
    for (int i = 0; i < 2; ++i)
        #pragma unroll
        for (int j = 0; j < 2; ++j) acc[i][j] = (f4v){0.f, 0.f, 0.f, 0.f};

    gl2lds16(A  + (size_t)(bm + w * 16 + lr) * C_ + lc, (char*)As + w * 1024);
    gl2lds16(Bt + (size_t)(bn + w * 16 + lr) * C_ + lc, (char*)Bs + w * 1024);

    for (int kt = 0; kt < 16; ++kt) {
        __syncthreads();
        const int buf = kt & 1;
        if (kt < 15) {
            const int nb = buf ^ 1, k0 = (kt + 1) * 32;
            gl2lds16(A  + (size_t)(bm + w * 16 + lr) * C_ + k0 + lc,
                     (char*)As + nb * 4096 + w * 1024);
            gl2lds16(Bt + (size_t)(bn + w * 16 + lr) * C_ + k0 + lc,
                     (char*)Bs + nb * 4096 + w * 1024);
        }
        s8v a[2], bfr[2];
        #pragma unroll
        for (int i = 0; i < 2; ++i) {
            const int row = wr * 32 + i * 16 + l16;
            a[i] = *(const s8v*)&As[buf][row >> 4][row & 15][q4 * 8];
        }
        #pragma unroll
        for (int j = 0; j < 2; ++j) {
            const int row = wc * 32 + j * 16 + l16;
            bfr[j] = *(const s8v*)&Bs[buf][row >> 4][row & 15][q4 * 8];
        }
        #pragma unroll
        for (int i = 0; i < 2; ++i)
            #pragma unroll
            for (int j = 0; j < 2; ++j)
                acc[i][j] = __builtin_amdgcn_mfma_f32_16x16x32_bf16(a[i], bfr[j], acc[i][j], 0, 0, 0);
    }

    #pragma unroll
    for (int j = 0; j < 2; ++j) {
        const int n = bn + wc * 32 + j * 16 + l16;
        const float bj = bias ? bias[n] : 0.0f;
        #pragma unroll
        for (int i = 0; i < 2; ++i) {
            const int m = bm + wr * 32 + i * 16 + q4 * 4;
            #pragma unroll
            for (int reg = 0; reg < 4; ++reg) {
                const float vv = acc[i][j][reg] + bj;
                if constexpr (OB) ((u16*)outv)[(size_t)(m + reg) * C_ + n] = f2b(vv);
                else              ((float*)outv)[(size_t)(m + reg) * C_ + n] = vv;
            }
        }
    }
}

// ---------------------------------------------------------------------------
// Fused QKV projection, 64x64 tiles, grid (24, 128) = 3072 blocks (~8/CU).
// which = nt>>3 selects {Wq,Wk,Wv}.
// K is written with a k-group XOR swizzle baked into the head dim: within
// each 32-wide half, the 16B group g of key s is stored at g ^ ((s>>2)&3)
// (= g ^ q4 here). attn's Ks ds_reads then spread over 4 group slots ->
// 2-way max bank conflict (free) instead of 8-way.
// V written TRANSPOSED + XOR-swizzled into Vt[b,h,d,s] (unchanged from r9).
// ---------------------------------------------------------------------------
__global__ __launch_bounds__(256) void qkv_k(const u16* __restrict__ A,
                                             const u16* __restrict__ Wq,
                                             const u16* __restrict__ Wk,
                                             const u16* __restrict__ Wv,
                                             u16* __restrict__ oq,
                                             u16* __restrict__ ok,
                                             u16* __restrict__ ovt)
{
    __shared__ u16 As[2][4][16][32];
    __shared__ u16 Bs[2][4][16][32];
    const int tid = threadIdx.x;
    const int lane = tid & 63, w = tid >> 6;
    const int q4 = lane >> 4, l16 = lane & 15;
    const int wr = w >> 1, wc = w & 1;
    const int nt = blockIdx.x, which = nt >> 3;
    const u16* Bt = which == 0 ? Wq : (which == 1 ? Wk : Wv);
    const int bm = blockIdx.y * 64, bn = (nt & 7) * 64;
    const int lr = lane >> 2, lc = (lane & 3) * 8;

    f4v acc[2][2];
    #pragma unroll
    for (int i = 0; i < 2; ++i)
        #pragma unroll
        for (int j = 0; j < 2; ++j) acc[i][j] = (f4v){0.f, 0.f, 0.f, 0.f};

    gl2lds16(A  + (size_t)(bm + w * 16 + lr) * C_ + lc, (char*)As + w * 1024);
    gl2lds16(Bt + (size_t)(bn + w * 16 + lr) * C_ + lc, (char*)Bs + w * 1024);

    for (int kt = 0; kt < 16; ++kt) {
        __syncthreads();
        const int buf = kt & 1;
        if (kt < 15) {
            const int nb = buf ^ 1, k0 = (kt + 1) * 32;
            gl2lds16(A  + (size_t)(bm + w * 16 + lr) * C_ + k0 + lc,
                     (char*)As + nb * 4096 + w * 1024);
            gl2lds16(Bt + (size_t)(bn + w * 16 + lr) * C_ + k0 + lc,
                     (char*)Bs + nb * 4096 + w * 1024);
        }
        s8v a[2], bfr[2];
        #pragma unroll
        for (int i = 0; i < 2; ++i) {
            const int row = wr * 32 + i * 16 + l16;
            a[i] = *(const s8v*)&As[buf][row >> 4][row & 15][q4 * 8];
        }
        #pragma unroll
        for (int j = 0; j < 2; ++j) {
            const int row = wc * 32 + j * 16 + l16;
            bfr[j] = *(const s8v*)&Bs[buf][row >> 4][row & 15][q4 * 8];
        }
        #pragma unroll
        for (int i = 0; i < 2; ++i)
            #pragma unroll
            for (int j = 0; j < 2; ++j)
                acc[i][j] = __builtin_amdgcn_mfma_f32_16x16x32_bf16(a[i], bfr[j], acc[i][j], 0, 0, 0);
    }

    if (which == 0) {
        #pragma unroll
        for (int j = 0; j < 2; ++j) {
            const int n = bn + wc * 32 + j * 16 + l16;
            #pragma unroll
            for (int i = 0; i < 2; ++i) {
                const int m = bm + wr * 32 + i * 16 + q4 * 4;
                #pragma unroll
                for (int reg = 0; reg < 4; ++reg)
                    oq[(size_t)(m + reg) * C_ + n] = f2b(acc[i][j][reg]);
            }
        }
    } else if (which == 1) {
        // K: column remapped by key swizzle. key s = m..m+3 (s>>2 == q4 mod 4).
        #pragma unroll
        for (int j = 0; j < 2; ++j) {
            const int n = bn + wc * 32 + j * 16 + l16;
            const int nswz = (n & ~31) | ((((n >> 3) & 3) ^ q4) << 3) | (n & 7);
            #pragma unroll
            for (int i = 0; i < 2; ++i) {
                const int m = bm + wr * 32 + i * 16 + q4 * 4;
                #pragma unroll
                for (int reg = 0; reg < 4; ++reg)
                    ok[(size_t)(m + reg) * C_ + nswz] = f2b(acc[i][j][reg]);
            }
        }
    } else {
        // V: transposed + swizzled write. m -> s, n -> (h,d).
        const int bglob = bm >> 11;
        const int sbase = bm & (S_ - 1);
        #pragma unroll
        for (int j = 0; j < 2; ++j) {
            const int n = bn + wc * 32 + j * 16 + l16;
            const int h = n >> 6, d = n & 63;
            u16* vrow = ovt + ((size_t)(bglob * H_ + h) * D_ + d) * S_;
            const int xw = d & 7;
            #pragma unroll
            for (int i = 0; i < 2; ++i) {
                const int s = sbase + wr * 32 + i * 16 + q4 * 4;
                const int pg = ((s & 31) >> 2) ^ xw;
                s4v pv;
                #pragma unroll
                for (int reg = 0; reg < 4; ++reg) pv[reg] = (short)f2b(acc[i][j][reg]);
                *(s4v*)&vrow[(s & ~31) + (pg << 2)] = pv;
            }
        }
    }
}

// ---------------------------------------------------------------------------
// bf16-chain LayerNorm kernels. One wave per row (lane holds 8 contiguous
// elements), 4 rows/block.
// ---------------------------------------------------------------------------
// in bf16 + res fp32 -> y1=LN(in+res)*w1+b1 (bf16 out1); y2=LN(y1)*w2+b2 (bf16 out2)
__global__ __launch_bounds__(256) void ln2xb_k(const u16* __restrict__ in,
                                               const float* __restrict__ res,
                                               const float* __restrict__ w1,
                                               const float* __restrict__ b1,
                                               const float* __restrict__ w2,
                                               const float* __restrict__ b2,
                                               u16* __restrict__ out1,
                                               u16* __restrict__ out2)
{
    const int lane = threadIdx.x & 63;
    const int row  = blockIdx.x * 4 + (threadIdx.x >> 6);
    const size_t off = (size_t)row * C_ + lane * 8;
    float v[8];
    b2f8(*(const s8v*)&in[off], v);
    {
        const float4 r0 = *(const float4*)&res[off];
        const float4 r1 = *(const float4*)&res[off + 4];
        v[0] += r0.x; v[1] += r0.y; v[2] += r0.z; v[3] += r0.w;
        v[4] += r1.x; v[5] += r1.y; v[6] += r1.z; v[7] += r1.w;
    }
    float s = 0.f, ss = 0.f;
    #pragma unroll
    for (int k = 0; k < 8; ++k) { s += v[k]; ss += v[k] * v[k]; }
    #pragma unroll
    for (int o = 32; o >= 1; o >>= 1) { s += __shfl_xor(s, o); ss += __shfl_xor(ss, o); }
    float mean = s * (1.0f / C_);
    float rstd = rsqrtf(ss * (1.0f / C_) - mean * mean + 1e-5f);

    const float4 wA0 = *(const float4*)&w1[lane * 8];
    const float4 wA1 = *(const float4*)&w1[lane * 8 + 4];
    const float4 bA0 = *(const float4*)&b1[lane * 8];
    const float4 bA1 = *(const float4*)&b1[lane * 8 + 4];
    const float wA[8] = {wA0.x, wA0.y, wA0.z, wA0.w, wA1.x, wA1.y, wA1.z, wA1.w};
    const float bA[8] = {bA0.x, bA0.y, bA0.z, bA0.w, bA1.x, bA1.y, bA1.z, bA1.w};
    float y[8];
    s8v o1;
    #pragma unroll
    for (int k = 0; k < 8; ++k) {
        y[k] = (v[k] - mean) * rstd * wA[k] + bA[k];
        o1[k] = (short)f2b(y[k]);
    }
    *(s8v*)&out1[off] = o1;

    s = 0.f; ss = 0.f;
    #pragma unroll
    for (int k = 0; k < 8; ++k) { s += y[k]; ss += y[k] * y[k]; }
    #pragma unroll
    for (int o = 32; o >= 1; o >>= 1) { s += __shfl_xor(s, o); ss += __shfl_xor(ss, o); }
    mean = s * (1.0f / C_);
    rstd = rsqrtf(ss * (1.0f / C_) - mean * mean + 1e-5f);

    const float4 wB0 = *(const float4*)&w2[lane * 8];
    const float4 wB1 = *(const float4*)&w2[lane * 8 + 4];
    const float4 bB0 = *(const float4*)&b2[lane * 8];
    const float4 bB1 = *(const float4*)&b2[lane * 8 + 4];
    const float wB[8] = {wB0.x, wB0.y, wB0.z, wB0.w, wB1.x, wB1.y, wB1.z, wB1.w};
    const float bB[8] = {bB0.x, bB0.y, bB0.z, bB0.w, bB1.x, bB1.y, bB1.z, bB1.w};
    s8v o2;
    #pragma unroll
    for (int k = 0; k < 8; ++k)
        o2[k] = (short)f2b((y[k] - mean) * rstd * wB[k] + bB[k]);
    *(s8v*)&out2[off] = o2;
}

// in bf16 -> LN -> bf16 out
__global__ __launch_bounds__(256) void lnb_k(const u16* __restrict__ in,
                                             const float* __restrict__ w,
                                             const float* __restrict__ bb,
                                             u16* __restrict__ out)
{
    const int lane = threadIdx.x & 63;
    const int row  = blockIdx.x * 4 + (threadIdx.x >> 6);
    const size_t off = (size_t)row * C_ + lane * 8;
    float v[8];
    b2f8(*(const s8v*)&in[off], v);
    float s = 0.f, ss = 0.f;
    #pragma unroll
    for (int k = 0; k < 8; ++k) { s += v[k]; ss += v[k] * v[k]; }
    #pragma unroll
    for (int o = 32; o >= 1; o >>= 1) { s += __shfl_xor(s, o); ss += __shfl_xor(ss, o); }
    const float mean = s * (1.0f / C_);
    const float rstd = rsqrtf(ss * (1.0f / C_) - mean * mean + 1e-5f);
    const float4 w0 = *(const float4*)&w[lane * 8];
    const float4 w1 = *(const float4*)&w[lane * 8 + 4];
    const float4 b0 = *(const float4*)&bb[lane * 8];
    const float4 b1 = *(const float4*)&bb[lane * 8 + 4];
    const float wv[8] = {w0.x, w0.y, w0.z, w0.w, w1.x, w1.y, w1.z, w1.w};
    const float bv[8] = {b0.x, b0.y, b0.z, b0.w, b1.x, b1.y, b1.z, b1.w};
    s8v o;
    #pragma unroll
    for (int k = 0; k < 8; ++k)
        o[k] = (short)f2b((v[k] - mean) * rstd * wv[k] + bv[k]);
    *(s8v*)&out[off] = o;
}

// in bf16 + res bf16 -> LN -> fp32 out
__global__ __launch_bounds__(256) void lnfin_k(const u16* __restrict__ in,
                                               const u16* __restrict__ res,
                                               const float* __restrict__ w,
                                               const float* __restrict__ bb,
                                               float* __restrict__ out)
{
    const int lane = threadIdx.x & 63;
    const int row  = blockIdx.x * 4 + (threadIdx.x >> 6);
    const size_t off = (size_t)row * C_ + lane * 8;
    float v[8], r[8];
    b2f8(*(const s8v*)&in[off], v);
    b2f8(*(const s8v*)&res[off], r);
    #pragma unroll
    for (int k = 0; k < 8; ++k) v[k] += r[k];
    float s = 0.f, ss = 0.f;
    #pragma unroll
    for (int k = 0; k < 8; ++k) { s += v[k]; ss += v[k] * v[k]; }
    #pragma unroll
    for (int o = 32; o >= 1; o >>= 1) { s += __shfl_xor(s, o); ss += __shfl_xor(ss, o); }
    const float mean = s * (1.0f / C_);
    const float rstd = rsqrtf(ss * (1.0f / C_) - mean * mean + 1e-5f);
    const float4 w0 = *(const float4*)&w[lane * 8];
    const float4 w1 = *(const float4*)&w[lane * 8 + 4];
    const float4 b0 = *(const float4*)&bb[lane * 8];
    const float4 b1 = *(const float4*)&bb[lane * 8 + 4];
    const float wv[8] = {w0.x, w0.y, w0.z, w0.w, w1.x, w1.y, w1.z, w1.w};
    const float bv[8] = {b0.x, b0.y, b0.z, b0.w, b1.x, b1.y, b1.z, b1.w};
    float4 o0, o1;
    o0.x = (v[0] - mean) * rstd * wv[0] + bv[0];
    o0.y = (v[1] - mean) * rstd * wv[1] + bv[1];
    o0.z = (v[2] - mean) * rstd * wv[2] + bv[2];
    o0.w = (v[3] - mean) * rstd * wv[3] + bv[3];
    o1.x = (v[4] - mean) * rstd * wv[4] + bv[4];
    o1.y = (v[5] - mean) * rstd * wv[5] + bv[5];
    o1.z = (v[6] - mean) * rstd * wv[6] + bv[6];
    o1.w = (v[7] - mean) * rstd * wv[7] + bv[7];
    *(float4*)&out[off]     = o0;
    *(float4*)&out[off + 4] = o1;
}

// ---------------------------------------------------------------------------
// Causal flash attention, register-resident P. grid (32,H,B), 256 thr;
// wave w owns queries w*16..w*16+15 of a 64-query tile. Transposed scores ->
// lane holds P in mfma_16x16x16 A-operand layout; PV from registers.
// Constant-max softmax (exact). K/V^T double-buffered via global_load_lds.
// BOTH K and V^T are globally pre-swizzled so all ds_reads are <=2-way.
// ---------------------------------------------------------------------------
__global__ __launch_bounds__(256) void attn_k(const u16* __restrict__ Q,
                                              const u16* __restrict__ K,
                                              const u16* __restrict__ Vt,
                                              u16* __restrict__ O)
{
    __shared__ u16 Ks[2][2][64][32];   // [buf][kh][key][k32] (k-group swizzled)
    __shared__ u16 Vs[2][2][64][32];   // [buf][keyhalf][d][key32] (swizzled)
    const int tid = threadIdx.x;
    const int lane = tid & 63, w = tid >> 6;
    const int q4 = lane >> 4, l16 = lane & 15;
    const int x = blockIdx.x, h = blockIdx.y, b = blockIdx.z;
    const int qb = (x & 1) ? 31 - (x >> 1) : (x >> 1);
    const size_t base  = ((size_t)b * S_) * C_ + h * D_;
    const size_t basev = ((size_t)(b * H_ + h)) * D_ * S_;
    const int lr = lane >> 2, lc = (lane & 3) * 8;
    const int kq = (q4 ^ ((l16 >> 2) & 3)) * 8;   // undo K k-group swizzle

    s8v qf[2];
    #pragma unroll
    for (int kh = 0; kh < 2; ++kh)
        qf[kh] = *(const s8v*)&Q[base + (size_t)(qb * 64 + w * 16 + l16) * C_ + kh * 32 + q4 * 8];

    #pragma unroll
    for (int r = 0; r < 2; ++r) {
        const int seg = r * 4 + w;
        const int row = (seg & 3) * 16 + lr;
        const int kh = seg >> 2;
        gl2lds16(K  + base  + (size_t)row * C_ + kh * 32 + lc, (char*)Ks + seg * 1024);
        gl2lds16(Vt + basev + (size_t)row * S_ + kh * 32 + lc, (char*)Vs + seg * 1024);
    }

    f4v o[4];
    float lp[4] = {0.f, 0.f, 0.f, 0.f};
    #pragma unroll
    for (int j = 0; j < 4; ++j) o[j] = (f4v){0.f, 0.f, 0.f, 0.f};

    const int qrow = w * 16 + l16;
    for (int kb = 0; kb <= qb; ++kb) {
        __syncthreads();
        const int buf = kb & 1;
        if (kb < qb) {
            const int nb = buf ^ 1, kn = kb + 1;
            #pragma unroll
            for (int r = 0; r < 2; ++r) {
                const int seg = r * 4 + w;
                const int row = (seg & 3) * 16 + lr;
                const int kh = seg >> 2;
                gl2lds16(K  + base  + (size_t)(kn * 64 + row) * C_ + kh * 32 + lc,
                         (char*)Ks + nb * 8192 + seg * 1024);
                gl2lds16(Vt + basev + (size_t)row * S_ + kn * 64 + kh * 32 + lc,
                         (char*)Vs + nb * 8192 + seg * 1024);
            }
        }

        f4v sc[4];
        #pragma unroll
        for (int j = 0; j < 4; ++j) sc[j] = (f4v){0.f, 0.f, 0.f, 0.f};
        #pragma unroll
        for (int kh = 0; kh < 2; ++kh) {
            #pragma unroll
            for (int j = 0; j < 4; ++j) {
                const s8v kf = *(const s8v*)&Ks[buf][kh][j * 16 + l16][kq];
                sc[j] = __builtin_amdgcn_mfma_f32_16x16x32_bf16(kf, qf[kh], sc[j], 0, 0, 0);
            }
        }

        const bool diag = (kb == qb);
        s4v pa[4];
        #pragma unroll
        for (int j = 0; j < 4; ++j) {
            float ps = 0.0f;
            #pragma unroll
            for (int reg = 0; reg < 4; ++reg) {
                float t = fmaf(sc[j][reg], 0.18033688011112043f, -11.541560327111707f);
                if (diag && (j * 16 + q4 * 4 + reg) > qrow) t = -128.0f;
                const float p = exp2f(t);
                ps += p;
                pa[j][reg] = (short)(__builtin_bit_cast(u32, p) >> 16);
            }
            lp[j] += ps;
        }

        #pragma unroll
        for (int c = 0; c < 4; ++c) {
            const int gh = (((c & 1) * 4 + q4) ^ (l16 & 7)) * 4;
            #pragma unroll
            for (int dj = 0; dj < 4; ++dj) {
                const s4v vb = *(const s4v*)&Vs[buf][c >> 1][dj * 16 + l16][gh];
                o[dj] = __builtin_amdgcn_mfma_f32_16x16x16bf16_1k(pa[c], vb, o[dj], 0, 0, 0);
            }
        }
    }

    float lt = (lp[0] + lp[1]) + (lp[2] + lp[3]);
    lt += __shfl_xor(lt, 16);
    lt += __shfl_xor(lt, 32);
    #pragma unroll
    for (int reg = 0; reg < 4; ++reg) {
        const float inv = 1.0f / __shfl(lt, q4 * 4 + reg);
        const size_t rowoff = base + (size_t)(qb * 64 + w * 16 + q4 * 4 + reg) * C_;
        #pragma unroll
        for (int dj = 0; dj < 4; ++dj)
            O[rowoff + dj * 16 + l16] = f2b(o[dj][reg] * inv);
    }
}

// ---------------------------------------------------------------------------
extern "C" void kernel_launch(void* const* d_in, const int* in_sizes, int n_in,
                              void* d_out, int out_size, void* d_ws, size_t ws_size,
                              hipStream_t stream)
{
    const float* x       = (const float*)d_in[0];
    const float* Wq      = (const float*)d_in[1];
    const float* Wk      = (const float*)d_in[2];
    const float* Wv      = (const float*)d_in[3];
    const float* Wo      = (const float*)d_in[4];
    const float* ln1_w   = (const float*)d_in[5];
    const float* ln1_b   = (const float*)d_in[6];
    const float* ffln1_w = (const float*)d_in[7];
    const float* ffln1_b = (const float*)d_in[8];
    const float* ff_w1   = (const float*)d_in[9];
    const float* ff_b1   = (const float*)d_in[10];
    const float* ffln2_w = (const float*)d_in[11];
    const float* ffln2_b = (const float*)d_in[12];
    const float* ff_w2   = (const float*)d_in[13];
    const float* ff_b2   = (const float*)d_in[14];
    const float* ln2_w   = (const float*)d_in[15];
    const float* ln2_b   = (const float*)d_in[16];
    float* out = (float*)d_out;

    const size_t MC = (size_t)M_ * C_;   // 4,194,304
    const size_t WW = (size_t)C_ * C_;
    u16* xb   = (u16*)d_ws;
    u16* WqT  = xb + MC;
    u16* WkT  = WqT + WW;
    u16* WvT  = WkT + WW;
    u16* WoT  = WvT + WW;
    u16* W1T  = WoT + WW;
    u16* W2T  = W1T + WW;
    u16* qbuf = W2T + WW;
    u16* kbuf = qbuf + MC;
    u16* vbuf = kbuf + MC;
    u16* vtbuf= vbuf + MC;
    u16*  abuf = xb;       // attn out; xb dead after qkv_k
    u16*  tf   = qbuf;     // bf16 chain intermediate (qbuf dead after attn)
    u16*  xln  = vbuf;     // bf16 x_ln (vbuf spare)

    const dim3 gg(C_ / 64, M_ / 64);     // (8, 128) = 1024 gemm blocks
    const dim3 gq(24, M_ / 64);          // fused QKV, 3072 blocks
    const dim3 ga(32, H_, B_);           // 1024 attn blocks (64-query tiles)
    const dim3 gt(16, 16, 6);            // all 6 weight transposes
    const int  gl = M_ / 4;

    conv_k<<<MC / 1024, 256, 0, stream>>>(x, xb);
    trconv6_k<<<gt, 256, 0, stream>>>(Wq, Wk, Wv, Wo, ff_w1, ff_w2,
                                      WqT, WkT, WvT, WoT, W1T, W2T);

    qkv_k<<<gq, 256, 0, stream>>>(xb, WqT, WkT, WvT, qbuf, kbuf, vtbuf);
    attn_k<<<ga, 256, 0, stream>>>(qbuf, kbuf, vtbuf, abuf);

    // t = a@Wo (bf16); xln = LN(t+x, ln1) bf16; xb = LN(xln, ffln1) bf16
    gemm_k<true><<<gg, 256, 0, stream>>>(abuf, WoT, nullptr, tf);
    ln2xb_k<<<gl, 256, 0, stream>>>(tf, x, ln1_w, ln1_b, ffln1_w, ffln1_b,
                                    xln, xb);
    // h1 = xb@W1 + b1 (bf16); xb = LN(h1, ffln2) bf16
    gemm_k<true><<<gg, 256, 0, stream>>>(xb, W1T, ff_b1, tf);
    lnb_k<<<gl, 256, 0, stream>>>(tf, ffln2_w, ffln2_b, xb);
    // h2 = xb@W2 + b2 (bf16); out = LN(h2 + xln, ln2) fp32
    gemm_k<true><<<gg, 256, 0, stream>>>(xb, W2T, ff_b2, tf);
    lnfin_k<<<gl, 256, 0, stream>>>(tf, xln, ln2_w, ln2_b, out);
}

// Round 11
// 258.403 us; speedup vs baseline: 2.1802x; 1.0197x over previous
//
#include <hip/hip_runtime.h>

#define B_ 4
#define S_ 2048
#define C_ 512
#define H_ 8
#define D_ 64
#define M_ 8192   // B_*S_

typedef short s8v __attribute__((ext_vector_type(8)));   // 8 bf16 (4 VGPRs)
typedef short s4v __attribute__((ext_vector_type(4)));   // 4 bf16 (2 VGPRs)
typedef float f4v __attribute__((ext_vector_type(4)));   // MFMA C/D
typedef unsigned short u16;
typedef unsigned int u32;

__device__ __forceinline__ u16 f2b(float f) {
    u32 u = __builtin_bit_cast(u32, f);
    u = u + 0x7fffu + ((u >> 16) & 1u);
    return (u16)(u >> 16);
}

__device__ __forceinline__ void b2f8(const s8v v, float* f) {
    #pragma unroll
    for (int k = 0; k < 8; ++k)
        f[k] = __builtin_bit_cast(float, (u32)(u16)v[k] << 16);
}

// async 16B global->LDS; lds dest is wave-uniform base, lane i lands at +16*i
__device__ __forceinline__ void gl2lds16(const void* g, void* l) {
    __builtin_amdgcn_global_load_lds(
        (const __attribute__((address_space(1))) void*)g,
        (__attribute__((address_space(3))) void*)l, 16, 0, 0);
}

// ---------------------------------------------------------------------------
// Combined prep: blocks [0,4096) convert x fp32->bf16; blocks [4096,5632)
// transpose+convert the 6 weight matrices (256 blocks each).
// ---------------------------------------------------------------------------
__global__ __launch_bounds__(256) void prep_k(const float* __restrict__ x,
                                              u16* __restrict__ xb,
                                              const float* __restrict__ s0,
                                              const float* __restrict__ s1,
                                              const float* __restrict__ s2,
                                              const float* __restrict__ s3,
                                              const float* __restrict__ s4,
                                              const float* __restrict__ s5,
                                              u16* __restrict__ d0,
                                              u16* __restrict__ d1,
                                              u16* __restrict__ d2,
                                              u16* __restrict__ d3,
                                              u16* __restrict__ d4,
                                              u16* __restrict__ d5)
{
    __shared__ float t[32][33];
    const int bx = blockIdx.x;
    if (bx < 4096) {
        const int i = (bx * 256 + (int)threadIdx.x) * 4;
        const float4 v = *(const float4*)&x[i];
        ushort4 o;
        o.x = f2b(v.x); o.y = f2b(v.y); o.z = f2b(v.z); o.w = f2b(v.w);
        *(ushort4*)&xb[i] = o;
        return;
    }
    const int tb = bx - 4096;
    const int z = tb >> 8, rem = tb & 255;
    const float* W; u16* Wt;
    switch (z) {
        case 0: W = s0; Wt = d0; break;
        case 1: W = s1; Wt = d1; break;
        case 2: W = s2; Wt = d2; break;
        case 3: W = s3; Wt = d3; break;
        case 4: W = s4; Wt = d4; break;
        default: W = s5; Wt = d5; break;
    }
    const int tx = threadIdx.x & 31, ty = threadIdx.x >> 5;
    const int n0 = (rem & 15) * 32, k0 = (rem >> 4) * 32;
    #pragma unroll
    for (int i = 0; i < 4; ++i)
        t[ty + i * 8][tx] = W[(size_t)(k0 + ty + i * 8) * C_ + n0 + tx];
    __syncthreads();
    #pragma unroll
    for (int i = 0; i < 4; ++i)
        Wt[(size_t)(n0 + ty + i * 8) * C_ + k0 + tx] = f2b(t[tx][ty + i * 8]);
}

// ---------------------------------------------------------------------------
// bf16 MFMA GEMM, 64x64 tile (1024 blocks -> 4/CU), BK=32, double-buffered.
// ---------------------------------------------------------------------------
template <bool OB>
__global__ __launch_bounds__(256) void gemm_k(const u16* __restrict__ A,
                                              const u16* __restrict__ Bt,
                                              const float* __restrict__ bias,
                                              void* __restrict__ outv)
{
    __shared__ u16 As[2][4][16][32];   // 4KB/buf
    __shared__ u16 Bs[2][4][16][32];
    const int tid = threadIdx.x;
    const int lane = tid & 63, w = tid >> 6;
    const int q4 = lane >> 4, l16 = lane & 15;
    const int wr = w >> 1, wc = w & 1;
    const int bm = blockIdx.y * 64, bn = blockIdx.x * 64;
    const int lr = lane >> 2, lc = (lane & 3) * 8;

    f4v acc[2][2];
    #pragma unroll
    for (int i = 0; i < 2; ++i)
        #pragma unroll
        for (int j = 0; j < 2; ++j) acc[i][j] = (f4v){0.f, 0.f, 0.f, 0.f};

    gl2lds16(A  + (size_t)(bm + w * 16 + lr) * C_ + lc, (char*)As + w * 1024);
    gl2lds16(Bt + (size_t)(bn + w * 16 + lr) * C_ + lc, (char*)Bs + w * 1024);

    for (int kt = 0; kt < 16; ++kt) {
        __syncthreads();
        const int buf = kt & 1;
        if (kt < 15) {
            const int nb = buf ^ 1, k0 = (kt + 1) * 32;
            gl2lds16(A  + (size_t)(bm + w * 16 + lr) * C_ + k0 + lc,
                     (char*)As + nb * 4096 + w * 1024);
            gl2lds16(Bt + (size_t)(bn + w * 16 + lr) * C_ + k0 + lc,
                     (char*)Bs + nb * 4096 + w * 1024);
        }
        s8v a[2], bfr[2];
        #pragma unroll
        for (int i = 0; i < 2; ++i) {
            const int row = wr * 32 + i * 16 + l16;
            a[i] = *(const s8v*)&As[buf][row >> 4][row & 15][q4 * 8];
        }
        #pragma unroll
        for (int j = 0; j < 2; ++j) {
            const int row = wc * 32 + j * 16 + l16;
            bfr[j] = *(const s8v*)&Bs[buf][row >> 4][row & 15][q4 * 8];
        }
        #pragma unroll
        for (int i = 0; i < 2; ++i)
            #pragma unroll
            for (int j = 0; j < 2; ++j)
                acc[i][j] = __builtin_amdgcn_mfma_f32_16x16x32_bf16(a[i], bfr[j], acc[i][j], 0, 0, 0);
    }

    #pragma unroll
    for (int j = 0; j < 2; ++j) {
        const int n = bn + wc * 32 + j * 16 + l16;
        const float bj = bias ? bias[n] : 0.0f;
        #pragma unroll
        for (int i = 0; i < 2; ++i) {
            const int m = bm + wr * 32 + i * 16 + q4 * 4;
            #pragma unroll
            for (int reg = 0; reg < 4; ++reg) {
                const float vv = acc[i][j][reg] + bj;
                if constexpr (OB) ((u16*)outv)[(size_t)(m + reg) * C_ + n] = f2b(vv);
                else              ((float*)outv)[(size_t)(m + reg) * C_ + n] = vv;
            }
        }
    }
}

// ---------------------------------------------------------------------------
// Fused QKV projection, 64x64 tiles, grid (24, 128) = 3072 blocks (~8/CU).
// which = nt>>3 selects {Wq,Wk,Wv}. K written with k-group XOR swizzle;
// V written TRANSPOSED + XOR-swizzled into Vt[b,h,d,s].
// ---------------------------------------------------------------------------
__global__ __launch_bounds__(256) void qkv_k(const u16* __restrict__ A,
                                             const u16* __restrict__ Wq,
                                             const u16* __restrict__ Wk,
                                             const u16* __restrict__ Wv,
                                             u16* __restrict__ oq,
                                             u16* __restrict__ ok,
                                             u16* __restrict__ ovt)
{
    __shared__ u16 As[2][4][16][32];
    __shared__ u16 Bs[2][4][16][32];
    const int tid = threadIdx.x;
    const int lane = tid & 63, w = tid >> 6;
    const int q4 = lane >> 4, l16 = lane & 15;
    const int wr = w >> 1, wc = w & 1;
    const int nt = blockIdx.x, which = nt >> 3;
    const u16* Bt = which == 0 ? Wq : (which == 1 ? Wk : Wv);
    const int bm = blockIdx.y * 64, bn = (nt & 7) * 64;
    const int lr = lane >> 2, lc = (lane & 3) * 8;

    f4v acc[2][2];
    #pragma unroll
    for (int i = 0; i < 2; ++i)
        #pragma unroll
        for (int j = 0; j < 2; ++j) acc[i][j] = (f4v){0.f, 0.f, 0.f, 0.f};

    gl2lds16(A  + (size_t)(bm + w * 16 + lr) * C_ + lc, (char*)As + w * 1024);
    gl2lds16(Bt + (size_t)(bn + w * 16 + lr) * C_ + lc, (char*)Bs + w * 1024);

    for (int kt = 0; kt < 16; ++kt) {
        __syncthreads();
        const int buf = kt & 1;
        if (kt < 15) {
            const int nb = buf ^ 1, k0 = (kt + 1) * 32;
            gl2lds16(A  + (size_t)(bm + w * 16 + lr) * C_ + k0 + lc,
                     (char*)As + nb * 4096 + w * 1024);
            gl2lds16(Bt + (size_t)(bn + w * 16 + lr) * C_ + k0 + lc,
                     (char*)Bs + nb * 4096 + w * 1024);
        }
        s8v a[2], bfr[2];
        #pragma unroll
        for (int i = 0; i < 2; ++i) {
            const int row = wr * 32 + i * 16 + l16;
            a[i] = *(const s8v*)&As[buf][row >> 4][row & 15][q4 * 8];
        }
        #pragma unroll
        for (int j = 0; j < 2; ++j) {
            const int row = wc * 32 + j * 16 + l16;
            bfr[j] = *(const s8v*)&Bs[buf][row >> 4][row & 15][q4 * 8];
        }
        #pragma unroll
        for (int i = 0; i < 2; ++i)
            #pragma unroll
            for (int j = 0; j < 2; ++j)
                acc[i][j] = __builtin_amdgcn_mfma_f32_16x16x32_bf16(a[i], bfr[j], acc[i][j], 0, 0, 0);
    }

    if (which == 0) {
        #pragma unroll
        for (int j = 0; j < 2; ++j) {
            const int n = bn + wc * 32 + j * 16 + l16;
            #pragma unroll
            for (int i = 0; i < 2; ++i) {
                const int m = bm + wr * 32 + i * 16 + q4 * 4;
                #pragma unroll
                for (int reg = 0; reg < 4; ++reg)
                    oq[(size_t)(m + reg) * C_ + n] = f2b(acc[i][j][reg]);
            }
        }
    } else if (which == 1) {
        #pragma unroll
        for (int j = 0; j < 2; ++j) {
            const int n = bn + wc * 32 + j * 16 + l16;
            const int nswz = (n & ~31) | ((((n >> 3) & 3) ^ q4) << 3) | (n & 7);
            #pragma unroll
            for (int i = 0; i < 2; ++i) {
                const int m = bm + wr * 32 + i * 16 + q4 * 4;
                #pragma unroll
                for (int reg = 0; reg < 4; ++reg)
                    ok[(size_t)(m + reg) * C_ + nswz] = f2b(acc[i][j][reg]);
            }
        }
    } else {
        const int bglob = bm >> 11;
        const int sbase = bm & (S_ - 1);
        #pragma unroll
        for (int j = 0; j < 2; ++j) {
            const int n = bn + wc * 32 + j * 16 + l16;
            const int h = n >> 6, d = n & 63;
            u16* vrow = ovt + ((size_t)(bglob * H_ + h) * D_ + d) * S_;
            const int xw = d & 7;
            #pragma unroll
            for (int i = 0; i < 2; ++i) {
                const int s = sbase + wr * 32 + i * 16 + q4 * 4;
                const int pg = ((s & 31) >> 2) ^ xw;
                s4v pv;
                #pragma unroll
                for (int reg = 0; reg < 4; ++reg) pv[reg] = (short)f2b(acc[i][j][reg]);
                *(s4v*)&vrow[(s & ~31) + (pg << 2)] = pv;
            }
        }
    }
}

// ---------------------------------------------------------------------------
// bf16-chain LayerNorm kernels. One wave per row, 4 rows/block.
// ---------------------------------------------------------------------------
__global__ __launch_bounds__(256) void ln2xb_k(const u16* __restrict__ in,
                                               const float* __restrict__ res,
                                               const float* __restrict__ w1,
                                               const float* __restrict__ b1,
                                               const float* __restrict__ w2,
                                               const float* __restrict__ b2,
                                               u16* __restrict__ out1,
                                               u16* __restrict__ out2)
{
    const int lane = threadIdx.x & 63;
    const int row  = blockIdx.x * 4 + (threadIdx.x >> 6);
    const size_t off = (size_t)row * C_ + lane * 8;
    float v[8];
    b2f8(*(const s8v*)&in[off], v);
    {
        const float4 r0 = *(const float4*)&res[off];
        const float4 r1 = *(const float4*)&res[off + 4];
        v[0] += r0.x; v[1] += r0.y; v[2] += r0.z; v[3] += r0.w;
        v[4] += r1.x; v[5] += r1.y; v[6] += r1.z; v[7] += r1.w;
    }
    float s = 0.f, ss = 0.f;
    #pragma unroll
    for (int k = 0; k < 8; ++k) { s += v[k]; ss += v[k] * v[k]; }
    #pragma unroll
    for (int o = 32; o >= 1; o >>= 1) { s += __shfl_xor(s, o); ss += __shfl_xor(ss, o); }
    float mean = s * (1.0f / C_);
    float rstd = rsqrtf(ss * (1.0f / C_) - mean * mean + 1e-5f);

    const float4 wA0 = *(const float4*)&w1[lane * 8];
    const float4 wA1 = *(const float4*)&w1[lane * 8 + 4];
    const float4 bA0 = *(const float4*)&b1[lane * 8];
    const float4 bA1 = *(const float4*)&b1[lane * 8 + 4];
    const float wA[8] = {wA0.x, wA0.y, wA0.z, wA0.w, wA1.x, wA1.y, wA1.z, wA1.w};
    const float bA[8] = {bA0.x, bA0.y, bA0.z, bA0.w, bA1.x, bA1.y, bA1.z, bA1.w};
    float y[8];
    s8v o1;
    #pragma unroll
    for (int k = 0; k < 8; ++k) {
        y[k] = (v[k] - mean) * rstd * wA[k] + bA[k];
        o1[k] = (short)f2b(y[k]);
    }
    *(s8v*)&out1[off] = o1;

    s = 0.f; ss = 0.f;
    #pragma unroll
    for (int k = 0; k < 8; ++k) { s += y[k]; ss += y[k] * y[k]; }
    #pragma unroll
    for (int o = 32; o >= 1; o >>= 1) { s += __shfl_xor(s, o); ss += __shfl_xor(ss, o); }
    mean = s * (1.0f / C_);
    rstd = rsqrtf(ss * (1.0f / C_) - mean * mean + 1e-5f);

    const float4 wB0 = *(const float4*)&w2[lane * 8];
    const float4 wB1 = *(const float4*)&w2[lane * 8 + 4];
    const float4 bB0 = *(const float4*)&b2[lane * 8];
    const float4 bB1 = *(const float4*)&b2[lane * 8 + 4];
    const float wB[8] = {wB0.x, wB0.y, wB0.z, wB0.w, wB1.x, wB1.y, wB1.z, wB1.w};
    const float bB[8] = {bB0.x, bB0.y, bB0.z, bB0.w, bB1.x, bB1.y, bB1.z, bB1.w};
    s8v o2;
    #pragma unroll
    for (int k = 0; k < 8; ++k)
        o2[k] = (short)f2b((y[k] - mean) * rstd * wB[k] + bB[k]);
    *(s8v*)&out2[off] = o2;
}

__global__ __launch_bounds__(256) void lnb_k(const u16* __restrict__ in,
                                             const float* __restrict__ w,
                                             const float* __restrict__ bb,
                                             u16* __restrict__ out)
{
    const int lane = threadIdx.x & 63;
    const int row  = blockIdx.x * 4 + (threadIdx.x >> 6);
    const size_t off = (size_t)row * C_ + lane * 8;
    float v[8];
    b2f8(*(const s8v*)&in[off], v);
    float s = 0.f, ss = 0.f;
    #pragma unroll
    for (int k = 0; k < 8; ++k) { s += v[k]; ss += v[k] * v[k]; }
    #pragma unroll
    for (int o = 32; o >= 1; o >>= 1) { s += __shfl_xor(s, o); ss += __shfl_xor(ss, o); }
    const float mean = s * (1.0f / C_);
    const float rstd = rsqrtf(ss * (1.0f / C_) - mean * mean + 1e-5f);
    const float4 w0 = *(const float4*)&w[lane * 8];
    const float4 w1 = *(const float4*)&w[lane * 8 + 4];
    const float4 b0 = *(const float4*)&bb[lane * 8];
    const float4 b1 = *(const float4*)&bb[lane * 8 + 4];
    const float wv[8] = {w0.x, w0.y, w0.z, w0.w, w1.x, w1.y, w1.z, w1.w};
    const float bv[8] = {b0.x, b0.y, b0.z, b0.w, b1.x, b1.y, b1.z, b1.w};
    s8v o;
    #pragma unroll
    for (int k = 0; k < 8; ++k)
        o[k] = (short)f2b((v[k] - mean) * rstd * wv[k] + bv[k]);
    *(s8v*)&out[off] = o;
}

__global__ __launch_bounds__(256) void lnfin_k(const u16* __restrict__ in,
                                               const u16* __restrict__ res,
                                               const float* __restrict__ w,
                                               const float* __restrict__ bb,
                                               float* __restrict__ out)
{
    const int lane = threadIdx.x & 63;
    const int row  = blockIdx.x * 4 + (threadIdx.x >> 6);
    const size_t off = (size_t)row * C_ + lane * 8;
    float v[8], r[8];
    b2f8(*(const s8v*)&in[off], v);
    b2f8(*(const s8v*)&res[off], r);
    #pragma unroll
    for (int k = 0; k < 8; ++k) v[k] += r[k];
    float s = 0.f, ss = 0.f;
    #pragma unroll
    for (int k = 0; k < 8; ++k) { s += v[k]; ss += v[k] * v[k]; }
    #pragma unroll
    for (int o = 32; o >= 1; o >>= 1) { s += __shfl_xor(s, o); ss += __shfl_xor(ss, o); }
    const float mean = s * (1.0f / C_);
    const float rstd = rsqrtf(ss * (1.0f / C_) - mean * mean + 1e-5f);
    const float4 w0 = *(const float4*)&w[lane * 8];
    const float4 w1 = *(const float4*)&w[lane * 8 + 4];
    const float4 b0 = *(const float4*)&bb[lane * 8];
    const float4 b1 = *(const float4*)&bb[lane * 8 + 4];
    const float wv[8] = {w0.x, w0.y, w0.z, w0.w, w1.x, w1.y, w1.z, w1.w};
    const float bv[8] = {b0.x, b0.y, b0.z, b0.w, b1.x, b1.y, b1.z, b1.w};
    float4 o0, o1;
    o0.x = (v[0] - mean) * rstd * wv[0] + bv[0];
    o0.y = (v[1] - mean) * rstd * wv[1] + bv[1];
    o0.z = (v[2] - mean) * rstd * wv[2] + bv[2];
    o0.w = (v[3] - mean) * rstd * wv[3] + bv[3];
    o1.x = (v[4] - mean) * rstd * wv[4] + bv[4];
    o1.y = (v[5] - mean) * rstd * wv[5] + bv[5];
    o1.z = (v[6] - mean) * rstd * wv[6] + bv[6];
    o1.w = (v[7] - mean) * rstd * wv[7] + bv[7];
    *(float4*)&out[off]     = o0;
    *(float4*)&out[off + 4] = o1;
}

// ---------------------------------------------------------------------------
// Causal flash attention, register-resident P. grid (32,H,B), 256 thr.
// LPT ordering: qb = 31 - blockIdx.x (heaviest blocks dispatch first ->
// scheduler backfills with light blocks, minimal tail).
// Diagonal tile peeled behind a uniform branch (non-diag path has no mask
// VALU ops). Transposed scores -> P in mfma_16x16x16 A-operand layout; PV
// from registers. Constant-max softmax (exact). K/V^T double-buffered via
// global_load_lds (both globally pre-swizzled).
// ---------------------------------------------------------------------------
__global__ __launch_bounds__(256) void attn_k(const u16* __restrict__ Q,
                                              const u16* __restrict__ K,
                                              const u16* __restrict__ Vt,
                                              u16* __restrict__ O)
{
    __shared__ u16 Ks[2][2][64][32];   // [buf][kh][key][k32] (k-group swizzled)
    __shared__ u16 Vs[2][2][64][32];   // [buf][keyhalf][d][key32] (swizzled)
    const int tid = threadIdx.x;
    const int lane = tid & 63, w = tid >> 6;
    const int q4 = lane >> 4, l16 = lane & 15;
    const int h = blockIdx.y, b = blockIdx.z;
    const int qb = 31 - (int)blockIdx.x;      // LPT: heavy first
    const size_t base  = ((size_t)b * S_) * C_ + h * D_;
    const size_t basev = ((size_t)(b * H_ + h)) * D_ * S_;
    const int lr = lane >> 2, lc = (lane & 3) * 8;
    const int kq = (q4 ^ ((l16 >> 2) & 3)) * 8;   // undo K k-group swizzle

    s8v qf[2];
    #pragma unroll
    for (int kh = 0; kh < 2; ++kh)
        qf[kh] = *(const s8v*)&Q[base + (size_t)(qb * 64 + w * 16 + l16) * C_ + kh * 32 + q4 * 8];

    #pragma unroll
    for (int r = 0; r < 2; ++r) {
        const int seg = r * 4 + w;
        const int row = (seg & 3) * 16 + lr;
        const int kh = seg >> 2;
        gl2lds16(K  + base  + (size_t)row * C_ + kh * 32 + lc, (char*)Ks + seg * 1024);
        gl2lds16(Vt + basev + (size_t)row * S_ + kh * 32 + lc, (char*)Vs + seg * 1024);
    }

    f4v o[4];
    float lp[4] = {0.f, 0.f, 0.f, 0.f};
    #pragma unroll
    for (int j = 0; j < 4; ++j) o[j] = (f4v){0.f, 0.f, 0.f, 0.f};

    const int qrow = w * 16 + l16;
    for (int kb = 0; kb <= qb; ++kb) {
        __syncthreads();
        const int buf = kb & 1;
        if (kb < qb) {
            const int nb = buf ^ 1, kn = kb + 1;
            #pragma unroll
            for (int r = 0; r < 2; ++r) {
                const int seg = r * 4 + w;
                const int row = (seg & 3) * 16 + lr;
                const int kh = seg >> 2;
                gl2lds16(K  + base  + (size_t)(kn * 64 + row) * C_ + kh * 32 + lc,
                         (char*)Ks + nb * 8192 + seg * 1024);
                gl2lds16(Vt + basev + (size_t)row * S_ + kn * 64 + kh * 32 + lc,
                         (char*)Vs + nb * 8192 + seg * 1024);
            }
        }

        f4v sc[4];
        #pragma unroll
        for (int j = 0; j < 4; ++j) sc[j] = (f4v){0.f, 0.f, 0.f, 0.f};
        #pragma unroll
        for (int kh = 0; kh < 2; ++kh) {
            #pragma unroll
            for (int j = 0; j < 4; ++j) {
                const s8v kf = *(const s8v*)&Ks[buf][kh][j * 16 + l16][kq];
                sc[j] = __builtin_amdgcn_mfma_f32_16x16x32_bf16(kf, qf[kh], sc[j], 0, 0, 0);
            }
        }

        s4v pa[4];
        if (kb == qb) {      // diagonal tile: masked path
            #pragma unroll
            for (int j = 0; j < 4; ++j) {
                float ps = 0.0f;
                #pragma unroll
                for (int reg = 0; reg < 4; ++reg) {
                    float t = fmaf(sc[j][reg], 0.18033688011112043f, -11.541560327111707f);
                    if ((j * 16 + q4 * 4 + reg) > qrow) t = -128.0f;
                    const float p = exp2f(t);
                    ps += p;
                    pa[j][reg] = (short)(__builtin_bit_cast(u32, p) >> 16);
                }
                lp[j] += ps;
            }
        } else {             // interior tile: no mask VALU
            #pragma unroll
            for (int j = 0; j < 4; ++j) {
                float ps = 0.0f;
                #pragma unroll
                for (int reg = 0; reg < 4; ++reg) {
                    const float p = exp2f(fmaf(sc[j][reg], 0.18033688011112043f,
                                               -11.541560327111707f));
                    ps += p;
                    pa[j][reg] = (short)(__builtin_bit_cast(u32, p) >> 16);
                }
                lp[j] += ps;
            }
        }

        #pragma unroll
        for (int c = 0; c < 4; ++c) {
            const int gh = (((c & 1) * 4 + q4) ^ (l16 & 7)) * 4;
            #pragma unroll
            for (int dj = 0; dj < 4; ++dj) {
                const s4v vb = *(const s4v*)&Vs[buf][c >> 1][dj * 16 + l16][gh];
                o[dj] = __builtin_amdgcn_mfma_f32_16x16x16bf16_1k(pa[c], vb, o[dj], 0, 0, 0);
            }
        }
    }

    float lt = (lp[0] + lp[1]) + (lp[2] + lp[3]);
    lt += __shfl_xor(lt, 16);
    lt += __shfl_xor(lt, 32);
    #pragma unroll
    for (int reg = 0; reg < 4; ++reg) {
        const float inv = 1.0f / __shfl(lt, q4 * 4 + reg);
        const size_t rowoff = base + (size_t)(qb * 64 + w * 16 + q4 * 4 + reg) * C_;
        #pragma unroll
        for (int dj = 0; dj < 4; ++dj)
            O[rowoff + dj * 16 + l16] = f2b(o[dj][reg] * inv);
    }
}

// ---------------------------------------------------------------------------
extern "C" void kernel_launch(void* const* d_in, const int* in_sizes, int n_in,
                              void* d_out, int out_size, void* d_ws, size_t ws_size,
                              hipStream_t stream)
{
    const float* x       = (const float*)d_in[0];
    const float* Wq      = (const float*)d_in[1];
    const float* Wk      = (const float*)d_in[2];
    const float* Wv      = (const float*)d_in[3];
    const float* Wo      = (const float*)d_in[4];
    const float* ln1_w   = (const float*)d_in[5];
    const float* ln1_b   = (const float*)d_in[6];
    const float* ffln1_w = (const float*)d_in[7];
    const float* ffln1_b = (const float*)d_in[8];
    const float* ff_w1   = (const float*)d_in[9];
    const float* ff_b1   = (const float*)d_in[10];
    const float* ffln2_w = (const float*)d_in[11];
    const float* ffln2_b = (const float*)d_in[12];
    const float* ff_w2   = (const float*)d_in[13];
    const float* ff_b2   = (const float*)d_in[14];
    const float* ln2_w   = (const float*)d_in[15];
    const float* ln2_b   = (const float*)d_in[16];
    float* out = (float*)d_out;

    const size_t MC = (size_t)M_ * C_;   // 4,194,304
    const size_t WW = (size_t)C_ * C_;
    u16* xb   = (u16*)d_ws;
    u16* WqT  = xb + MC;
    u16* WkT  = WqT + WW;
    u16* WvT  = WkT + WW;
    u16* WoT  = WvT + WW;
    u16* W1T  = WoT + WW;
    u16* W2T  = W1T + WW;
    u16* qbuf = W2T + WW;
    u16* kbuf = qbuf + MC;
    u16* vbuf = kbuf + MC;
    u16* vtbuf= vbuf + MC;
    u16*  abuf = xb;       // attn out; xb dead after qkv_k
    u16*  tf   = qbuf;     // bf16 chain intermediate (qbuf dead after attn)
    u16*  xln  = vbuf;     // bf16 x_ln (vbuf spare)

    const dim3 gg(C_ / 64, M_ / 64);     // (8, 128) = 1024 gemm blocks
    const dim3 gq(24, M_ / 64);          // fused QKV, 3072 blocks
    const dim3 ga(32, H_, B_);           // 1024 attn blocks (LPT-ordered)
    const int  gl = M_ / 4;

    prep_k<<<5632, 256, 0, stream>>>(x, xb, Wq, Wk, Wv, Wo, ff_w1, ff_w2,
                                     WqT, WkT, WvT, WoT, W1T, W2T);

    qkv_k<<<gq, 256, 0, stream>>>(xb, WqT, WkT, WvT, qbuf, kbuf, vtbuf);
    attn_k<<<ga, 256, 0, stream>>>(qbuf, kbuf, vtbuf, abuf);

    // t = a@Wo (bf16); xln = LN(t+x, ln1) bf16; xb = LN(xln, ffln1) bf16
    gemm_k<true><<<gg, 256, 0, stream>>>(abuf, WoT, nullptr, tf);
    ln2xb_k<<<gl, 256, 0, stream>>>(tf, x, ln1_w, ln1_b, ffln1_w, ffln1_b,
                                    xln, xb);
    // h1 = xb@W1 + b1 (bf16); xb = LN(h1, ffln2) bf16
    gemm_k<true><<<gg, 256, 0, stream>>>(xb, W1T, ff_b1, tf);
    lnb_k<<<gl, 256, 0, stream>>>(tf, ffln2_w, ffln2_b, xb);
    // h2 = xb@W2 + b2 (bf16); out = LN(h2 + xln, ln2) fp32
    gemm_k<true><<<gg, 256, 0, stream>>>(xb, W2T, ff_b2, tf);
    lnfin_k<<<gl, 256, 0, stream>>>(tf, xln, ln2_w, ln2_b, out);
}